// Round 1
// baseline (1392.323 us; speedup 1.0000x reference)
//
#include <hip/hip_runtime.h>
#include <hip/hip_bf16.h>

#define N_NODES 50000
#define N_EDGES 800000
#define IN_F    256
#define H_HEADS 4
#define F_OUT   64
#define HF      256   // H_HEADS * F_OUT
#define SLOPE   0.2f

static inline size_t align256(size_t x) { return (x + 255) & ~(size_t)255; }

__device__ __forceinline__ unsigned fkey(float f) {
  unsigned u = __float_as_uint(f);
  return (u & 0x80000000u) ? ~u : (u | 0x80000000u);
}
__device__ __forceinline__ float fdec(unsigned k) {
  unsigned u = (k & 0x80000000u) ? (k & 0x7FFFFFFFu) : ~k;
  return __uint_as_float(u);
}
__device__ __forceinline__ float lrelu(float x) { return x > 0.f ? x : SLOPE * x; }

// ---------------- GEMM: h = feat(50000x256) @ W(256x256), f32 ----------------
__global__ __launch_bounds__(256) void gemm_kernel(
    const float* __restrict__ A, const float* __restrict__ B, float* __restrict__ C) {
  __shared__ float As[16][132];
  __shared__ float Bs[16][128];
  int tid = threadIdx.x;
  int bm = blockIdx.x * 128, bn = blockIdx.y * 128;
  int tx = tid & 15, ty = tid >> 4;
  float acc[8][8];
#pragma unroll
  for (int i = 0; i < 8; ++i)
#pragma unroll
    for (int j = 0; j < 8; ++j) acc[i][j] = 0.f;

  int la_r = (tid * 8) >> 4;   // 0..127
  int la_k = (tid * 8) & 15;   // 0 or 8
  int lb_k = (tid * 8) >> 7;   // 0..15
  int lb_c = (tid * 8) & 127;

  for (int k0 = 0; k0 < 256; k0 += 16) {
    float4 va0, va1;
    int gr = bm + la_r;
    if (gr < N_NODES) {
      const float* ap = A + (size_t)gr * 256 + k0 + la_k;
      va0 = *(const float4*)ap; va1 = *(const float4*)(ap + 4);
    } else {
      va0 = make_float4(0, 0, 0, 0); va1 = va0;
    }
    As[la_k + 0][la_r] = va0.x; As[la_k + 1][la_r] = va0.y;
    As[la_k + 2][la_r] = va0.z; As[la_k + 3][la_r] = va0.w;
    As[la_k + 4][la_r] = va1.x; As[la_k + 5][la_r] = va1.y;
    As[la_k + 6][la_r] = va1.z; As[la_k + 7][la_r] = va1.w;

    const float* bp = B + (size_t)(k0 + lb_k) * 256 + bn + lb_c;
    float4 vb0 = *(const float4*)bp, vb1 = *(const float4*)(bp + 4);
    *(float4*)&Bs[lb_k][lb_c] = vb0; *(float4*)&Bs[lb_k][lb_c + 4] = vb1;
    __syncthreads();
#pragma unroll
    for (int kk = 0; kk < 16; ++kk) {
      float a[8], b[8];
#pragma unroll
      for (int i = 0; i < 8; ++i) a[i] = As[kk][ty * 8 + i];
#pragma unroll
      for (int j = 0; j < 8; ++j) b[j] = Bs[kk][tx * 8 + j];
#pragma unroll
      for (int i = 0; i < 8; ++i)
#pragma unroll
        for (int j = 0; j < 8; ++j) acc[i][j] = fmaf(a[i], b[j], acc[i][j]);
    }
    __syncthreads();
  }
#pragma unroll
  for (int i = 0; i < 8; ++i) {
    int r = bm + ty * 8 + i;
    if (r < N_NODES) {
      float4* cp = (float4*)(C + (size_t)r * 256 + bn + tx * 8);
      cp[0] = make_float4(acc[i][0], acc[i][1], acc[i][2], acc[i][3]);
      cp[1] = make_float4(acc[i][4], acc[i][5], acc[i][6], acc[i][7]);
    }
  }
}

// ------------- per-node dots: el, er, al (block = node, wave = head) ---------
__global__ __launch_bounds__(256) void node_dots(
    const float* __restrict__ hbuf, const float* __restrict__ attn_l,
    const float* __restrict__ attn_r, const float* __restrict__ hop_attn_l,
    float* __restrict__ el, float* __restrict__ er, float* __restrict__ al) {
  int n = blockIdx.x, t = threadIdx.x;
  int hh = t >> 6, f = t & 63;
  float x = hbuf[(size_t)n * HF + t];
  float pl = x * attn_l[t], pr = x * attn_r[t], pa = x * hop_attn_l[t];
#pragma unroll
  for (int off = 32; off; off >>= 1) {
    pl += __shfl_xor(pl, off);
    pr += __shfl_xor(pr, off);
    pa += __shfl_xor(pa, off);
  }
  if (f == 0) {
    el[n * 4 + hh] = pl; er[n * 4 + hh] = pr; al[n * 4 + hh] = pa;
  }
}

// ---------------- degree histograms ----------------
__global__ void hist_kernel(const int* __restrict__ src, const int* __restrict__ dst,
                            int* __restrict__ cnt_in, int* __restrict__ cnt_out) {
  int e = blockIdx.x * blockDim.x + threadIdx.x;
  if (e >= N_EDGES) return;
  atomicAdd(&cnt_in[dst[e]], 1);
  atomicAdd(&cnt_out[src[e]], 1);
}

// ---------------- exclusive scan of cnt_in -> row_ptr (single block) ---------
__global__ __launch_bounds__(1024) void scan_kernel(const int* __restrict__ cnt,
                                                    int* __restrict__ row_ptr, int n) {
  __shared__ int wsum[16];
  __shared__ int carry_s;
  if (threadIdx.x == 0) carry_s = 0;
  __syncthreads();
  const int T = 1024;
  for (int base = 0; base < n; base += T) {
    int i = base + threadIdx.x;
    int v = (i < n) ? cnt[i] : 0;
    int lane = threadIdx.x & 63, wid = threadIdx.x >> 6;
    int x = v;
#pragma unroll
    for (int off = 1; off < 64; off <<= 1) {
      int y = __shfl_up(x, off, 64);
      if (lane >= off) x += y;
    }
    if (lane == 63) wsum[wid] = x;
    __syncthreads();
    if (threadIdx.x < 16) {
      int s = wsum[threadIdx.x];
#pragma unroll
      for (int off = 1; off < 16; off <<= 1) {
        int y = __shfl_up(s, off, 16);
        if ((int)(threadIdx.x & 15) >= off) s += y;
      }
      wsum[threadIdx.x] = s;
    }
    __syncthreads();
    int carry = carry_s;
    int pre = (wid > 0) ? wsum[wid - 1] : 0;
    int incl = x + pre + carry;
    if (i < n) row_ptr[i] = incl - v;
    __syncthreads();
    if (threadIdx.x == T - 1) carry_s = incl;
    __syncthreads();
  }
  if (threadIdx.x == 0) row_ptr[n] = carry_s;
}

// ---------------- degree norms ----------------
__global__ void norms_kernel(const int* __restrict__ cnt_in, const int* __restrict__ cnt_out,
                             float* __restrict__ norm_in, float* __restrict__ norm_out) {
  int n = blockIdx.x * blockDim.x + threadIdx.x;
  if (n >= N_NODES) return;
  float od = (float)max(cnt_out[n], 1);
  float id = (float)max(cnt_in[n], 1);
  norm_out[n] = rsqrtf(od);
  norm_in[n] = sqrtf(id);
}

// ---------------- edge logits + segment max (encoded atomicMax) --------------
__global__ void edge_logits(const int* __restrict__ src, const int* __restrict__ dst,
                            const float* __restrict__ el, const float* __restrict__ er,
                            float* __restrict__ eval,
                            unsigned* __restrict__ max_src, unsigned* __restrict__ max_dst) {
  int e = blockIdx.x * blockDim.x + threadIdx.x;
  if (e >= N_EDGES) return;
  int s = src[e], d = dst[e];
  float4 l4 = *(const float4*)&el[s * 4];
  float4 r4 = *(const float4*)&er[d * 4];
  float v[4] = {l4.x + r4.x, l4.y + r4.y, l4.z + r4.z, l4.w + r4.w};
  float4 o;
  float* op = (float*)&o;
#pragma unroll
  for (int h = 0; h < 4; ++h) {
    float x = lrelu(v[h]);
    op[h] = x;
    unsigned k = fkey(x);
    atomicMax(&max_src[s * 4 + h], k);
    atomicMax(&max_dst[d * 4 + h], k);
  }
  *(float4*)&eval[(size_t)e * 4] = o;
}

// ---------------- exp + segment sums ----------------
__global__ void edge_sums(const int* __restrict__ src, const int* __restrict__ dst,
                          const float* __restrict__ eval,
                          const unsigned* __restrict__ max_src, const unsigned* __restrict__ max_dst,
                          float* __restrict__ sum_src, float* __restrict__ sum_dst) {
  int e = blockIdx.x * blockDim.x + threadIdx.x;
  if (e >= N_EDGES) return;
  int s = src[e], d = dst[e];
  float4 ev = *(const float4*)&eval[(size_t)e * 4];
  const float* evp = (const float*)&ev;
#pragma unroll
  for (int h = 0; h < 4; ++h) {
    float ms = fdec(max_src[s * 4 + h]);
    float md = fdec(max_dst[d * 4 + h]);
    atomicAdd(&sum_src[s * 4 + h], expf(evp[h] - ms));
    atomicAdd(&sum_dst[d * 4 + h], expf(evp[h] - md));
  }
}

// ---------------- attention coefficient a (in-place over eval) ---------------
__global__ void edge_a(const int* __restrict__ src, const int* __restrict__ dst,
                       float* __restrict__ eval,
                       const unsigned* __restrict__ max_src, const unsigned* __restrict__ max_dst,
                       const float* __restrict__ sum_src, const float* __restrict__ sum_dst,
                       const float* __restrict__ sigma) {
  int e = blockIdx.x * blockDim.x + threadIdx.x;
  if (e >= N_EDGES) return;
  float sg = 1.f / (1.f + expf(-sigma[0]));
  int s = src[e], d = dst[e];
  float4 ev = *(const float4*)&eval[(size_t)e * 4];
  const float* evp = (const float*)&ev;
  float4 o;
  float* op = (float*)&o;
#pragma unroll
  for (int h = 0; h < 4; ++h) {
    float ms = fdec(max_src[s * 4 + h]);
    float md = fdec(max_dst[d * 4 + h]);
    float as_ = fmaxf(expf(evp[h] - ms) / sum_src[s * 4 + h], 1e-10f);
    float ad_ = fmaxf(expf(evp[h] - md) / sum_dst[d * 4 + h], 1e-10f);
    op[h] = expf(sg * logf(ad_) + (1.f - sg) * logf(as_));
  }
  *(float4*)&eval[(size_t)e * 4] = o;
}

// -------- CSR fill: col + per-edge weight w = a * norm_out[src] --------------
__global__ void fill_kernel(const int* __restrict__ src, const int* __restrict__ dst,
                            const int* __restrict__ row_ptr, int* __restrict__ fill_cnt,
                            const float* __restrict__ a_edge, const float* __restrict__ norm_out,
                            int* __restrict__ col, float* __restrict__ w_csr) {
  int e = blockIdx.x * blockDim.x + threadIdx.x;
  if (e >= N_EDGES) return;
  int s = src[e], d = dst[e];
  int pos = row_ptr[d] + atomicAdd(&fill_cnt[d], 1);
  col[pos] = s;
  float no = norm_out[s];
  float4 a4 = *(const float4*)&a_edge[(size_t)e * 4];
  *(float4*)&w_csr[(size_t)pos * 4] = make_float4(a4.x * no, a4.y * no, a4.z * no, a4.w * no);
}

// -------- one hop of weighted SpMM: wave per dst node, lane = f --------------
__global__ __launch_bounds__(256) void hop_kernel(
    const float* __restrict__ xin, float* __restrict__ xout,
    const int* __restrict__ row_ptr, const int* __restrict__ col,
    const float* __restrict__ w, const float* __restrict__ norm_in) {
  int wave = (int)((blockIdx.x * blockDim.x + threadIdx.x) >> 6);
  int lane = threadIdx.x & 63;
  if (wave >= N_NODES) return;
  int d = wave;
  int beg = row_ptr[d], end = row_ptr[d + 1];
  float acc0 = 0.f, acc1 = 0.f, acc2 = 0.f, acc3 = 0.f;
  for (int p = beg; p < end; ++p) {
    int s = col[p];
    float4 wt = *(const float4*)&w[(size_t)p * 4];
    const float* xp = &xin[(size_t)s * HF + lane];
    acc0 = fmaf(wt.x, xp[0],   acc0);
    acc1 = fmaf(wt.y, xp[64],  acc1);
    acc2 = fmaf(wt.z, xp[128], acc2);
    acc3 = fmaf(wt.w, xp[192], acc3);
  }
  float ni = norm_in[d];
  float* op = &xout[(size_t)d * HF + lane];
  op[0]   = acc0 * ni;
  op[64]  = acc1 * ni;
  op[128] = acc2 * ni;
  op[192] = acc3 * ni;
}

// -------- hop-attention softmax over {h, x1, x2, x3} + combine ---------------
__global__ __launch_bounds__(256) void final_combine(
    const float* __restrict__ h0, const float* __restrict__ x1,
    const float* __restrict__ x2, const float* __restrict__ x3,
    const float* __restrict__ al, const float* __restrict__ hop_attn_r,
    float* __restrict__ out) {
  int n = blockIdx.x, t = threadIdx.x;
  size_t idx = (size_t)n * HF + t;
  float v0 = h0[idx], v1 = x1[idx], v2 = x2[idx], v3 = x3[idx];
  float wr = hop_attn_r[t];
  float b0 = v0 * wr, b1 = v1 * wr, b2 = v2 * wr, b3 = v3 * wr;
#pragma unroll
  for (int off = 32; off; off >>= 1) {
    b0 += __shfl_xor(b0, off);
    b1 += __shfl_xor(b1, off);
    b2 += __shfl_xor(b2, off);
    b3 += __shfl_xor(b3, off);
  }
  float a0 = al[n * 4 + (t >> 6)];
  b0 = lrelu(b0 + a0); b1 = lrelu(b1 + a0); b2 = lrelu(b2 + a0); b3 = lrelu(b3 + a0);
  float m = fmaxf(fmaxf(b0, b1), fmaxf(b2, b3));
  float e0 = expf(b0 - m), e1 = expf(b1 - m), e2 = expf(b2 - m), e3 = expf(b3 - m);
  float inv = 1.f / (e0 + e1 + e2 + e3);
  out[idx] = (v0 * e0 + v1 * e1 + v2 * e2 + v3 * e3) * inv;
}

extern "C" void kernel_launch(void* const* d_in, const int* in_sizes, int n_in,
                              void* d_out, int out_size, void* d_ws, size_t ws_size,
                              hipStream_t stream) {
  const float* feat       = (const float*)d_in[0];
  const int*   src        = (const int*)d_in[1];
  const int*   dst        = (const int*)d_in[2];
  const float* W          = (const float*)d_in[3];
  const float* attn_l     = (const float*)d_in[4];
  const float* attn_r     = (const float*)d_in[5];
  const float* hop_attn_l = (const float*)d_in[6];
  const float* hop_attn_r = (const float*)d_in[7];
  const float* sigma      = (const float*)d_in[8];
  float* out = (float*)d_out;

  char* ws = (char*)d_ws;
  size_t off = 0;
  auto alloc = [&](size_t bytes) -> void* {
    void* p = ws + off;
    off = align256(off + bytes);
    return p;
  };
  float* hbuf   = (float*)alloc((size_t)N_NODES * HF * 4);      // hop 0
  float* x1     = (float*)alloc((size_t)N_NODES * HF * 4);      // hop 1
  float* x2     = (float*)alloc((size_t)N_NODES * HF * 4);      // hop 2  (hop 3 -> d_out)
  float* a_edge = (float*)alloc((size_t)N_EDGES * 4 * 4);       // e logits, then a (in-place)
  float* w_csr  = (float*)alloc((size_t)N_EDGES * 4 * 4);       // CSR edge weights [pos][h]
  int*   col    = (int*)alloc((size_t)N_EDGES * 4);
  int*   row_ptr= (int*)alloc((size_t)(N_NODES + 1) * 4);
  float* el     = (float*)alloc((size_t)N_NODES * 4 * 4);
  float* er     = (float*)alloc((size_t)N_NODES * 4 * 4);
  float* al     = (float*)alloc((size_t)N_NODES * 4 * 4);
  float* norm_out = (float*)alloc((size_t)N_NODES * 4);
  float* norm_in  = (float*)alloc((size_t)N_NODES * 4);
  size_t zoff = off;                                            // zero-init region start
  unsigned* max_src = (unsigned*)alloc((size_t)N_NODES * 4 * 4);
  unsigned* max_dst = (unsigned*)alloc((size_t)N_NODES * 4 * 4);
  float* sum_src  = (float*)alloc((size_t)N_NODES * 4 * 4);
  float* sum_dst  = (float*)alloc((size_t)N_NODES * 4 * 4);
  int* cnt_in   = (int*)alloc((size_t)N_NODES * 4);
  int* cnt_out  = (int*)alloc((size_t)N_NODES * 4);
  int* fill_cnt = (int*)alloc((size_t)N_NODES * 4);
  size_t zbytes = off - zoff;

  hipMemsetAsync(ws + zoff, 0, zbytes, stream);

  // h = feat @ W
  gemm_kernel<<<dim3((N_NODES + 127) / 128, 2), 256, 0, stream>>>(feat, W, hbuf);
  // el, er, al
  node_dots<<<N_NODES, 256, 0, stream>>>(hbuf, attn_l, attn_r, hop_attn_l, el, er, al);
  // degrees + CSR skeleton
  const int EB = (N_EDGES + 255) / 256;
  hist_kernel<<<EB, 256, 0, stream>>>(src, dst, cnt_in, cnt_out);
  scan_kernel<<<1, 1024, 0, stream>>>(cnt_in, row_ptr, N_NODES);
  norms_kernel<<<(N_NODES + 255) / 256, 256, 0, stream>>>(cnt_in, cnt_out, norm_in, norm_out);
  // edge softmax pipeline
  edge_logits<<<EB, 256, 0, stream>>>(src, dst, el, er, a_edge, max_src, max_dst);
  edge_sums<<<EB, 256, 0, stream>>>(src, dst, a_edge, max_src, max_dst, sum_src, sum_dst);
  edge_a<<<EB, 256, 0, stream>>>(src, dst, a_edge, max_src, max_dst, sum_src, sum_dst, sigma);
  // CSR fill with folded norm_out[src]
  fill_kernel<<<EB, 256, 0, stream>>>(src, dst, row_ptr, fill_cnt, a_edge, norm_out, col, w_csr);
  // K = 3 hops (wave per dst row)
  const int HB = (N_NODES * 64 + 255) / 256;
  hop_kernel<<<HB, 256, 0, stream>>>(hbuf, x1, row_ptr, col, w_csr, norm_in);
  hop_kernel<<<HB, 256, 0, stream>>>(x1, x2, row_ptr, col, w_csr, norm_in);
  hop_kernel<<<HB, 256, 0, stream>>>(x2, out, row_ptr, col, w_csr, norm_in);
  // hop-attention combine (reads x3 from d_out, overwrites in place)
  final_combine<<<N_NODES, 256, 0, stream>>>(hbuf, x1, x2, out, al, hop_attn_r, out);
}

// Round 2
// 919.932 us; speedup vs baseline: 1.5135x; 1.5135x over previous
//
#include <hip/hip_runtime.h>
#include <hip/hip_bf16.h>

#define N_NODES 50000
#define N_EDGES 800000
#define IN_F    256
#define H_HEADS 4
#define F_OUT   64
#define HF      256   // H_HEADS * F_OUT
#define SLOPE   0.2f

static inline size_t align256(size_t x) { return (x + 255) & ~(size_t)255; }

__device__ __forceinline__ float lrelu(float x) { return x > 0.f ? x : SLOPE * x; }

// ---------------- GEMM: h = feat(50000x256) @ W(256x256), f32 ----------------
__global__ __launch_bounds__(256) void gemm_kernel(
    const float* __restrict__ A, const float* __restrict__ B, float* __restrict__ C) {
  __shared__ float As[16][132];
  __shared__ float Bs[16][128];
  int tid = threadIdx.x;
  int bm = blockIdx.x * 128, bn = blockIdx.y * 128;
  int tx = tid & 15, ty = tid >> 4;
  float acc[8][8];
#pragma unroll
  for (int i = 0; i < 8; ++i)
#pragma unroll
    for (int j = 0; j < 8; ++j) acc[i][j] = 0.f;

  int la_r = (tid * 8) >> 4;   // 0..127
  int la_k = (tid * 8) & 15;   // 0 or 8
  int lb_k = (tid * 8) >> 7;   // 0..15
  int lb_c = (tid * 8) & 127;

  for (int k0 = 0; k0 < 256; k0 += 16) {
    float4 va0, va1;
    int gr = bm + la_r;
    if (gr < N_NODES) {
      const float* ap = A + (size_t)gr * 256 + k0 + la_k;
      va0 = *(const float4*)ap; va1 = *(const float4*)(ap + 4);
    } else {
      va0 = make_float4(0, 0, 0, 0); va1 = va0;
    }
    As[la_k + 0][la_r] = va0.x; As[la_k + 1][la_r] = va0.y;
    As[la_k + 2][la_r] = va0.z; As[la_k + 3][la_r] = va0.w;
    As[la_k + 4][la_r] = va1.x; As[la_k + 5][la_r] = va1.y;
    As[la_k + 6][la_r] = va1.z; As[la_k + 7][la_r] = va1.w;

    const float* bp = B + (size_t)(k0 + lb_k) * 256 + bn + lb_c;
    float4 vb0 = *(const float4*)bp, vb1 = *(const float4*)(bp + 4);
    *(float4*)&Bs[lb_k][lb_c] = vb0; *(float4*)&Bs[lb_k][lb_c + 4] = vb1;
    __syncthreads();
#pragma unroll
    for (int kk = 0; kk < 16; ++kk) {
      float a[8], b[8];
#pragma unroll
      for (int i = 0; i < 8; ++i) a[i] = As[kk][ty * 8 + i];
#pragma unroll
      for (int j = 0; j < 8; ++j) b[j] = Bs[kk][tx * 8 + j];
#pragma unroll
      for (int i = 0; i < 8; ++i)
#pragma unroll
        for (int j = 0; j < 8; ++j) acc[i][j] = fmaf(a[i], b[j], acc[i][j]);
    }
    __syncthreads();
  }
#pragma unroll
  for (int i = 0; i < 8; ++i) {
    int r = bm + ty * 8 + i;
    if (r < N_NODES) {
      float4* cp = (float4*)(C + (size_t)r * 256 + bn + tx * 8);
      cp[0] = make_float4(acc[i][0], acc[i][1], acc[i][2], acc[i][3]);
      cp[1] = make_float4(acc[i][4], acc[i][5], acc[i][6], acc[i][7]);
    }
  }
}

// ------------- per-node dots: el, er, al (block = node, wave = head) ---------
__global__ __launch_bounds__(256) void node_dots(
    const float* __restrict__ hbuf, const float* __restrict__ attn_l,
    const float* __restrict__ attn_r, const float* __restrict__ hop_attn_l,
    float* __restrict__ el, float* __restrict__ er, float* __restrict__ al) {
  int n = blockIdx.x, t = threadIdx.x;
  int hh = t >> 6, f = t & 63;
  float x = hbuf[(size_t)n * HF + t];
  float pl = x * attn_l[t], pr = x * attn_r[t], pa = x * hop_attn_l[t];
#pragma unroll
  for (int off = 32; off; off >>= 1) {
    pl += __shfl_xor(pl, off);
    pr += __shfl_xor(pr, off);
    pa += __shfl_xor(pa, off);
  }
  if (f == 0) {
    el[n * 4 + hh] = pl; er[n * 4 + hh] = pr; al[n * 4 + hh] = pa;
  }
}

// ---------------- degree histograms ----------------
__global__ void hist_kernel(const int* __restrict__ src, const int* __restrict__ dst,
                            int* __restrict__ cnt_in, int* __restrict__ cnt_out) {
  int e = blockIdx.x * blockDim.x + threadIdx.x;
  if (e >= N_EDGES) return;
  atomicAdd(&cnt_in[dst[e]], 1);
  atomicAdd(&cnt_out[src[e]], 1);
}

// ------- exclusive scan (single block per array; block 0: in, 1: out) --------
__global__ __launch_bounds__(1024) void scan_kernel(
    const int* __restrict__ cnt_in, int* __restrict__ row_ptr,
    const int* __restrict__ cnt_out, int* __restrict__ col_ptr, int n) {
  const int* cnt = (blockIdx.x == 0) ? cnt_in : cnt_out;
  int* outp = (blockIdx.x == 0) ? row_ptr : col_ptr;
  __shared__ int wsum[16];
  __shared__ int carry_s;
  if (threadIdx.x == 0) carry_s = 0;
  __syncthreads();
  const int T = 1024;
  for (int base = 0; base < n; base += T) {
    int i = base + threadIdx.x;
    int v = (i < n) ? cnt[i] : 0;
    int lane = threadIdx.x & 63, wid = threadIdx.x >> 6;
    int x = v;
#pragma unroll
    for (int off = 1; off < 64; off <<= 1) {
      int y = __shfl_up(x, off, 64);
      if (lane >= off) x += y;
    }
    if (lane == 63) wsum[wid] = x;
    __syncthreads();
    if (threadIdx.x < 16) {
      int s = wsum[threadIdx.x];
#pragma unroll
      for (int off = 1; off < 16; off <<= 1) {
        int y = __shfl_up(s, off, 16);
        if ((int)(threadIdx.x & 15) >= off) s += y;
      }
      wsum[threadIdx.x] = s;
    }
    __syncthreads();
    int carry = carry_s;
    int pre = (wid > 0) ? wsum[wid - 1] : 0;
    int incl = x + pre + carry;
    if (i < n) outp[i] = incl - v;
    __syncthreads();
    if (threadIdx.x == T - 1) carry_s = incl;
    __syncthreads();
  }
  if (threadIdx.x == 0) outp[n] = carry_s;
}

// ---------------- degree norms ----------------
__global__ void norms_kernel(const int* __restrict__ cnt_in, const int* __restrict__ cnt_out,
                             float* __restrict__ norm_in, float* __restrict__ norm_out) {
  int n = blockIdx.x * blockDim.x + threadIdx.x;
  if (n >= N_NODES) return;
  float od = (float)max(cnt_out[n], 1);
  float id = (float)max(cnt_in[n], 1);
  norm_out[n] = rsqrtf(od);
  norm_in[n] = sqrtf(id);
}

// ------- build CSR (dst-grouped: col=src) and CSC (src-grouped: row=dst) -----
__global__ void fill2_kernel(const int* __restrict__ src, const int* __restrict__ dst,
                             const int* __restrict__ row_ptr, const int* __restrict__ col_ptr,
                             int* __restrict__ fc_in, int* __restrict__ fc_out,
                             int* __restrict__ col, int* __restrict__ row) {
  int e = blockIdx.x * blockDim.x + threadIdx.x;
  if (e >= N_EDGES) return;
  int s = src[e], d = dst[e];
  int p1 = row_ptr[d] + atomicAdd(&fc_in[d], 1);
  col[p1] = s;
  int p2 = col_ptr[s] + atomicAdd(&fc_out[s], 1);
  row[p2] = d;
}

// ---- per-(node,head) online softmax stats over its edge segment (no atomics)
// dst-grouped call: ptr=row_ptr idxarr=col  own=er other=el
// src-grouped call: ptr=col_ptr idxarr=row  own=el other=er
__global__ __launch_bounds__(256) void seg_stats(
    const int* __restrict__ ptr, const int* __restrict__ idxarr,
    const float* __restrict__ own, const float* __restrict__ other,
    float* __restrict__ mx, float* __restrict__ sm) {
  int t = blockIdx.x * blockDim.x + threadIdx.x;
  if (t >= N_NODES * 4) return;
  int n = t >> 2, h = t & 3;
  float o = own[n * 4 + h];
  int beg = ptr[n], end = ptr[n + 1];
  float m = -1e30f, s = 0.f;
  for (int p = beg; p < end; ++p) {
    int u = idxarr[p];
    float e = lrelu(other[u * 4 + h] + o);
    float mn = fmaxf(m, e);
    s = s * __expf(m - mn) + __expf(e - mn);
    m = mn;
  }
  mx[t] = m;
  sm[t] = s;
}

// ---- per-(dst,head): final attention coeff + folded norm -> w_csr -----------
__global__ __launch_bounds__(256) void csr_weights(
    const int* __restrict__ row_ptr, const int* __restrict__ col,
    const float* __restrict__ el, const float* __restrict__ er,
    const float* __restrict__ m_src, const float* __restrict__ s_src,
    const float* __restrict__ m_dst, const float* __restrict__ s_dst,
    const float* __restrict__ norm_out, const float* __restrict__ sigma,
    float* __restrict__ w) {
  int t = blockIdx.x * blockDim.x + threadIdx.x;
  if (t >= N_NODES * 4) return;
  int d = t >> 2, h = t & 3;
  float sg = 1.f / (1.f + __expf(-sigma[0]));
  float er_d = er[d * 4 + h];
  float md = m_dst[d * 4 + h], sd = s_dst[d * 4 + h];
  int beg = row_ptr[d], end = row_ptr[d + 1];
  for (int p = beg; p < end; ++p) {
    int s_ = col[p];
    float e = lrelu(el[s_ * 4 + h] + er_d);
    float as_ = fmaxf(__expf(e - m_src[s_ * 4 + h]) / s_src[s_ * 4 + h], 1e-10f);
    float ad_ = fmaxf(__expf(e - md) / sd, 1e-10f);
    float a = __expf(sg * __logf(ad_) + (1.f - sg) * __logf(as_));
    w[(size_t)p * 4 + h] = a * norm_out[s_];
  }
}

// -------- one hop of weighted SpMM: wave per dst node, lane = f --------------
__global__ __launch_bounds__(256) void hop_kernel(
    const float* __restrict__ xin, float* __restrict__ xout,
    const int* __restrict__ row_ptr, const int* __restrict__ col,
    const float* __restrict__ w, const float* __restrict__ norm_in) {
  int wave = (int)((blockIdx.x * blockDim.x + threadIdx.x) >> 6);
  int lane = threadIdx.x & 63;
  if (wave >= N_NODES) return;
  int d = wave;
  int beg = row_ptr[d], end = row_ptr[d + 1];
  float acc0 = 0.f, acc1 = 0.f, acc2 = 0.f, acc3 = 0.f;
  for (int p = beg; p < end; ++p) {
    int s = col[p];
    float4 wt = *(const float4*)&w[(size_t)p * 4];
    const float* xp = &xin[(size_t)s * HF + lane];
    acc0 = fmaf(wt.x, xp[0],   acc0);
    acc1 = fmaf(wt.y, xp[64],  acc1);
    acc2 = fmaf(wt.z, xp[128], acc2);
    acc3 = fmaf(wt.w, xp[192], acc3);
  }
  float ni = norm_in[d];
  float* op = &xout[(size_t)d * HF + lane];
  op[0]   = acc0 * ni;
  op[64]  = acc1 * ni;
  op[128] = acc2 * ni;
  op[192] = acc3 * ni;
}

// -------- hop-attention softmax over {h, x1, x2, x3} + combine ---------------
__global__ __launch_bounds__(256) void final_combine(
    const float* __restrict__ h0, const float* __restrict__ x1,
    const float* __restrict__ x2, const float* __restrict__ x3,
    const float* __restrict__ al, const float* __restrict__ hop_attn_r,
    float* __restrict__ out) {
  int n = blockIdx.x, t = threadIdx.x;
  size_t idx = (size_t)n * HF + t;
  float v0 = h0[idx], v1 = x1[idx], v2 = x2[idx], v3 = x3[idx];
  float wr = hop_attn_r[t];
  float b0 = v0 * wr, b1 = v1 * wr, b2 = v2 * wr, b3 = v3 * wr;
#pragma unroll
  for (int off = 32; off; off >>= 1) {
    b0 += __shfl_xor(b0, off);
    b1 += __shfl_xor(b1, off);
    b2 += __shfl_xor(b2, off);
    b3 += __shfl_xor(b3, off);
  }
  float a0 = al[n * 4 + (t >> 6)];
  b0 = lrelu(b0 + a0); b1 = lrelu(b1 + a0); b2 = lrelu(b2 + a0); b3 = lrelu(b3 + a0);
  float m = fmaxf(fmaxf(b0, b1), fmaxf(b2, b3));
  float e0 = expf(b0 - m), e1 = expf(b1 - m), e2 = expf(b2 - m), e3 = expf(b3 - m);
  float inv = 1.f / (e0 + e1 + e2 + e3);
  out[idx] = (v0 * e0 + v1 * e1 + v2 * e2 + v3 * e3) * inv;
}

extern "C" void kernel_launch(void* const* d_in, const int* in_sizes, int n_in,
                              void* d_out, int out_size, void* d_ws, size_t ws_size,
                              hipStream_t stream) {
  const float* feat       = (const float*)d_in[0];
  const int*   src        = (const int*)d_in[1];
  const int*   dst        = (const int*)d_in[2];
  const float* W          = (const float*)d_in[3];
  const float* attn_l     = (const float*)d_in[4];
  const float* attn_r     = (const float*)d_in[5];
  const float* hop_attn_l = (const float*)d_in[6];
  const float* hop_attn_r = (const float*)d_in[7];
  const float* sigma      = (const float*)d_in[8];
  float* out = (float*)d_out;

  char* ws = (char*)d_ws;
  size_t off = 0;
  auto alloc = [&](size_t bytes) -> void* {
    void* p = ws + off;
    off = align256(off + bytes);
    return p;
  };
  float* hbuf   = (float*)alloc((size_t)N_NODES * HF * 4);      // hop 0
  float* x1     = (float*)alloc((size_t)N_NODES * HF * 4);      // hop 1
  float* x2     = (float*)alloc((size_t)N_NODES * HF * 4);      // hop 2  (hop 3 -> d_out)
  float* w_csr  = (float*)alloc((size_t)N_EDGES * 4 * 4);       // CSR edge weights [pos][h]
  int*   col    = (int*)alloc((size_t)N_EDGES * 4);             // CSR: src per position
  int*   row    = (int*)alloc((size_t)N_EDGES * 4);             // CSC: dst per position
  int*   row_ptr= (int*)alloc((size_t)(N_NODES + 1) * 4);
  int*   col_ptr= (int*)alloc((size_t)(N_NODES + 1) * 4);
  float* el     = (float*)alloc((size_t)N_NODES * 4 * 4);
  float* er     = (float*)alloc((size_t)N_NODES * 4 * 4);
  float* al     = (float*)alloc((size_t)N_NODES * 4 * 4);
  float* norm_out = (float*)alloc((size_t)N_NODES * 4);
  float* norm_in  = (float*)alloc((size_t)N_NODES * 4);
  float* m_src  = (float*)alloc((size_t)N_NODES * 4 * 4);
  float* s_src  = (float*)alloc((size_t)N_NODES * 4 * 4);
  float* m_dst  = (float*)alloc((size_t)N_NODES * 4 * 4);
  float* s_dst  = (float*)alloc((size_t)N_NODES * 4 * 4);
  size_t zoff = off;                                            // zero-init region start
  int* cnt_in   = (int*)alloc((size_t)N_NODES * 4);
  int* cnt_out  = (int*)alloc((size_t)N_NODES * 4);
  int* fc_in    = (int*)alloc((size_t)N_NODES * 4);
  int* fc_out   = (int*)alloc((size_t)N_NODES * 4);
  size_t zbytes = off - zoff;

  hipMemsetAsync(ws + zoff, 0, zbytes, stream);

  // h = feat @ W
  gemm_kernel<<<dim3((N_NODES + 127) / 128, 2), 256, 0, stream>>>(feat, W, hbuf);
  // el, er, al
  node_dots<<<N_NODES, 256, 0, stream>>>(hbuf, attn_l, attn_r, hop_attn_l, el, er, al);
  // degrees + CSR/CSC skeletons
  const int EB = (N_EDGES + 255) / 256;
  hist_kernel<<<EB, 256, 0, stream>>>(src, dst, cnt_in, cnt_out);
  scan_kernel<<<2, 1024, 0, stream>>>(cnt_in, row_ptr, cnt_out, col_ptr, N_NODES);
  norms_kernel<<<(N_NODES + 255) / 256, 256, 0, stream>>>(cnt_in, cnt_out, norm_in, norm_out);
  fill2_kernel<<<EB, 256, 0, stream>>>(src, dst, row_ptr, col_ptr, fc_in, fc_out, col, row);
  // node-centric edge-softmax stats (no atomics)
  const int NT = (N_NODES * 4 + 255) / 256;
  seg_stats<<<NT, 256, 0, stream>>>(row_ptr, col, er, el, m_dst, s_dst);   // dst-grouped
  seg_stats<<<NT, 256, 0, stream>>>(col_ptr, row, el, er, m_src, s_src);   // src-grouped
  // final per-edge weights into CSR order
  csr_weights<<<NT, 256, 0, stream>>>(row_ptr, col, el, er, m_src, s_src, m_dst, s_dst,
                                      norm_out, sigma, w_csr);
  // K = 3 hops (wave per dst row)
  const int HB = (N_NODES * 64 + 255) / 256;
  hop_kernel<<<HB, 256, 0, stream>>>(hbuf, x1, row_ptr, col, w_csr, norm_in);
  hop_kernel<<<HB, 256, 0, stream>>>(x1, x2, row_ptr, col, w_csr, norm_in);
  hop_kernel<<<HB, 256, 0, stream>>>(x2, out, row_ptr, col, w_csr, norm_in);
  // hop-attention combine (reads x3 from d_out, overwrites in place)
  final_combine<<<N_NODES, 256, 0, stream>>>(hbuf, x1, x2, out, al, hop_attn_r, out);
}

// Round 3
// 868.977 us; speedup vs baseline: 1.6023x; 1.0586x over previous
//
#include <hip/hip_runtime.h>
#include <hip/hip_bf16.h>

#define N_NODES 50000
#define N_EDGES 800000
#define HF      256   // H_HEADS * F_OUT
#define SLOPE   0.2f
#define BIN_W   1024
#define NBINS   49    // ceil(N_NODES / BIN_W)

static inline size_t align256(size_t x) { return (x + 255) & ~(size_t)255; }

__device__ __forceinline__ float lrelu(float x) { return x > 0.f ? x : SLOPE * x; }

// ---------------- GEMM: h = feat(50000x256) @ W(256x256), f32 ----------------
__global__ __launch_bounds__(256) void gemm_kernel(
    const float* __restrict__ A, const float* __restrict__ B, float* __restrict__ C) {
  __shared__ float As[16][132];
  __shared__ float Bs[16][128];
  int tid = threadIdx.x;
  int bm = blockIdx.x * 128, bn = blockIdx.y * 128;
  int tx = tid & 15, ty = tid >> 4;
  float acc[8][8];
#pragma unroll
  for (int i = 0; i < 8; ++i)
#pragma unroll
    for (int j = 0; j < 8; ++j) acc[i][j] = 0.f;

  int la_r = (tid * 8) >> 4;
  int la_k = (tid * 8) & 15;
  int lb_k = (tid * 8) >> 7;
  int lb_c = (tid * 8) & 127;

  for (int k0 = 0; k0 < 256; k0 += 16) {
    float4 va0, va1;
    int gr = bm + la_r;
    if (gr < N_NODES) {
      const float* ap = A + (size_t)gr * 256 + k0 + la_k;
      va0 = *(const float4*)ap; va1 = *(const float4*)(ap + 4);
    } else {
      va0 = make_float4(0, 0, 0, 0); va1 = va0;
    }
    As[la_k + 0][la_r] = va0.x; As[la_k + 1][la_r] = va0.y;
    As[la_k + 2][la_r] = va0.z; As[la_k + 3][la_r] = va0.w;
    As[la_k + 4][la_r] = va1.x; As[la_k + 5][la_r] = va1.y;
    As[la_k + 6][la_r] = va1.z; As[la_k + 7][la_r] = va1.w;

    const float* bp = B + (size_t)(k0 + lb_k) * 256 + bn + lb_c;
    float4 vb0 = *(const float4*)bp, vb1 = *(const float4*)(bp + 4);
    *(float4*)&Bs[lb_k][lb_c] = vb0; *(float4*)&Bs[lb_k][lb_c + 4] = vb1;
    __syncthreads();
#pragma unroll
    for (int kk = 0; kk < 16; ++kk) {
      float a[8], b[8];
#pragma unroll
      for (int i = 0; i < 8; ++i) a[i] = As[kk][ty * 8 + i];
#pragma unroll
      for (int j = 0; j < 8; ++j) b[j] = Bs[kk][tx * 8 + j];
#pragma unroll
      for (int i = 0; i < 8; ++i)
#pragma unroll
        for (int j = 0; j < 8; ++j) acc[i][j] = fmaf(a[i], b[j], acc[i][j]);
    }
    __syncthreads();
  }
#pragma unroll
  for (int i = 0; i < 8; ++i) {
    int r = bm + ty * 8 + i;
    if (r < N_NODES) {
      float4* cp = (float4*)(C + (size_t)r * 256 + bn + tx * 8);
      cp[0] = make_float4(acc[i][0], acc[i][1], acc[i][2], acc[i][3]);
      cp[1] = make_float4(acc[i][4], acc[i][5], acc[i][6], acc[i][7]);
    }
  }
}

// ------------- per-node dots: el, er, al ------------------------------------
__global__ __launch_bounds__(256) void node_dots(
    const float* __restrict__ hbuf, const float* __restrict__ attn_l,
    const float* __restrict__ attn_r, const float* __restrict__ hop_attn_l,
    float* __restrict__ el, float* __restrict__ er, float* __restrict__ al) {
  int n = blockIdx.x, t = threadIdx.x;
  int hh = t >> 6, f = t & 63;
  float x = hbuf[(size_t)n * HF + t];
  float pl = x * attn_l[t], pr = x * attn_r[t], pa = x * hop_attn_l[t];
#pragma unroll
  for (int off = 32; off; off >>= 1) {
    pl += __shfl_xor(pl, off);
    pr += __shfl_xor(pr, off);
    pa += __shfl_xor(pa, off);
  }
  if (f == 0) {
    el[n * 4 + hh] = pl; er[n * 4 + hh] = pr; al[n * 4 + hh] = pa;
  }
}

// -------- pass A: per-bin edge histograms (LDS-aggregated) -------------------
__global__ __launch_bounds__(256) void bin_hist(
    const int* __restrict__ src, const int* __restrict__ dst,
    int* __restrict__ binA, int* __restrict__ binB) {
  __shared__ int cA[NBINS], cB[NBINS];
  int t = threadIdx.x;
  if (t < NBINS) { cA[t] = 0; cB[t] = 0; }
  __syncthreads();
  int e = blockIdx.x * 256 + t;            // grid covers exactly N_EDGES
  int s = src[e], d = dst[e];
  atomicAdd(&cA[d >> 10], 1);
  atomicAdd(&cB[s >> 10], 1);
  __syncthreads();
  if (t < NBINS) {
    if (cA[t]) atomicAdd(&binA[t], cA[t]);
    if (cB[t]) atomicAdd(&binB[t], cB[t]);
  }
}

// -------- pass B: scan bin counts -> bases + alloc cursors -------------------
__global__ void bin_scan(const int* __restrict__ binA, const int* __restrict__ binB,
                         int* __restrict__ baseA, int* __restrict__ baseB,
                         int* __restrict__ allocA, int* __restrict__ allocB,
                         int* __restrict__ row_ptr, int* __restrict__ col_ptr) {
  int t = threadIdx.x;  // 64 threads, one wave
  int vA = (t < NBINS) ? binA[t] : 0;
  int vB = (t < NBINS) ? binB[t] : 0;
  int xA = vA, xB = vB;
#pragma unroll
  for (int off = 1; off < 64; off <<= 1) {
    int yA = __shfl_up(xA, off);
    int yB = __shfl_up(xB, off);
    if (t >= off) { xA += yA; xB += yB; }
  }
  if (t < NBINS) {
    baseA[t] = xA - vA; allocA[t] = xA - vA;
    baseB[t] = xB - vB; allocB[t] = xB - vB;
  }
  if (t == NBINS - 1) {
    baseA[NBINS] = xA; baseB[NBINS] = xB;
    row_ptr[N_NODES] = N_EDGES; col_ptr[N_NODES] = N_EDGES;
  }
}

// -------- pass C: chunked binning of 8B edge records -------------------------
__global__ __launch_bounds__(256) void bin_scatter(
    const int* __restrict__ src, const int* __restrict__ dst,
    int* __restrict__ allocA, int* __restrict__ allocB,
    int2* __restrict__ recA, int2* __restrict__ recB) {
  __shared__ int cA[NBINS], cB[NBINS], bA[NBINS], bB[NBINS];
  int t = threadIdx.x;
  if (t < NBINS) { cA[t] = 0; cB[t] = 0; }
  __syncthreads();
  int e = blockIdx.x * 256 + t;
  int s = src[e], d = dst[e];
  int ba = d >> 10, bb = s >> 10;
  int ra = atomicAdd(&cA[ba], 1);
  int rb = atomicAdd(&cB[bb], 1);
  __syncthreads();
  if (t < NBINS) {
    bA[t] = cA[t] ? atomicAdd(&allocA[t], cA[t]) : 0;
    bB[t] = cB[t] ? atomicAdd(&allocB[t], cB[t]) : 0;
  }
  __syncthreads();
  recA[bA[ba] + ra] = make_int2(s, d);  // payload=src, key=dst
  recB[bB[bb] + rb] = make_int2(d, s);  // payload=dst, key=src
}

// -------- pass D: in-LDS counting sort per bin -> ptr + payload arrays -------
__global__ __launch_bounds__(256) void bin_sort(
    const int2* __restrict__ recA, const int* __restrict__ baseA,
    int* __restrict__ row_ptr, int* __restrict__ outA,
    const int2* __restrict__ recB, const int* __restrict__ baseB,
    int* __restrict__ col_ptr, int* __restrict__ outB) {
  const int2* rec; const int* base; int* ptr; int* out;
  if (blockIdx.y == 0) { rec = recA; base = baseA; ptr = row_ptr; out = outA; }
  else                 { rec = recB; base = baseB; ptr = col_ptr; out = outB; }
  __shared__ int hist[BIN_W];
  __shared__ int wsum[4];
  int b = blockIdx.x, t = threadIdx.x;
  int n0 = b << 10;
  int nn = min(BIN_W, N_NODES - n0);
  int beg = base[b], end = base[b + 1];
  for (int i = t; i < BIN_W; i += 256) hist[i] = 0;
  __syncthreads();
  for (int p = beg + t; p < end; p += 256)
    atomicAdd(&hist[rec[p].y - n0], 1);
  __syncthreads();
  int i0 = t * 4;
  int h0 = hist[i0], h1 = hist[i0 + 1], h2 = hist[i0 + 2], h3 = hist[i0 + 3];
  int sum4 = h0 + h1 + h2 + h3;
  int x = sum4;
  int lane = t & 63, wid = t >> 6;
#pragma unroll
  for (int off = 1; off < 64; off <<= 1) {
    int y = __shfl_up(x, off);
    if (lane >= off) x += y;
  }
  if (lane == 63) wsum[wid] = x;
  __syncthreads();
  int wpre = 0;
#pragma unroll
  for (int wj = 0; wj < 4; ++wj) wpre += (wj < wid) ? wsum[wj] : 0;
  int excl = wpre + x - sum4;            // exclusive prefix of this 4-group
  int e0 = excl, e1 = excl + h0, e2 = excl + h0 + h1, e3 = excl + h0 + h1 + h2;
  hist[i0] = e0; hist[i0 + 1] = e1; hist[i0 + 2] = e2; hist[i0 + 3] = e3;
  if (i0 + 0 < nn) ptr[n0 + i0 + 0] = beg + e0;
  if (i0 + 1 < nn) ptr[n0 + i0 + 1] = beg + e1;
  if (i0 + 2 < nn) ptr[n0 + i0 + 2] = beg + e2;
  if (i0 + 3 < nn) ptr[n0 + i0 + 3] = beg + e3;
  __syncthreads();
  for (int p = beg + t; p < end; p += 256) {
    int2 r = rec[p];
    int pos = atomicAdd(&hist[r.y - n0], 1);
    out[beg + pos] = r.x;
  }
}

// ---------------- norm_in from row_ptr diffs ---------------------------------
__global__ void norm_in_kernel(const int* __restrict__ row_ptr, float* __restrict__ norm_in) {
  int n = blockIdx.x * blockDim.x + threadIdx.x;
  if (n >= N_NODES) return;
  int deg = row_ptr[n + 1] - row_ptr[n];
  norm_in[n] = sqrtf((float)max(deg, 1));
}

// ---- per-(node,head) softmax-denominator log-coefficients (no max needed) ---
// mode 0 (dst-grouped): out = sg*ln(S_d)
// mode 1 (src-grouped): out = (1-sg)*ln(S_s) + 0.5*ln(max(outdeg,1))  [folds norm_out]
__global__ __launch_bounds__(256) void seg_stats(
    const int* __restrict__ ptr, const int* __restrict__ payload,
    const float* __restrict__ own, const float* __restrict__ other,
    const float* __restrict__ sigma, int mode, float* __restrict__ outc) {
  int t = blockIdx.x * blockDim.x + threadIdx.x;
  if (t >= N_NODES * 4) return;
  int n = t >> 2, h = t & 3;
  float sg = 1.f / (1.f + __expf(-sigma[0]));
  float coef = mode ? (1.f - sg) : sg;
  float o = own[n * 4 + h];
  int beg = ptr[n], end = ptr[n + 1];
  float s = 0.f;
  for (int p = beg; p < end; ++p) {
    int u = payload[p];
    s += __expf(lrelu(other[u * 4 + h] + o));
  }
  float c = coef * __logf(s);
  if (mode) c += 0.5f * __logf((float)max(end - beg, 1));
  outc[t] = c;
}

// ---- per-(dst,head): w = exp(e - cd - cs) (one exp per edge-head) -----------
__global__ __launch_bounds__(256) void csr_weights(
    const int* __restrict__ row_ptr, const int* __restrict__ col,
    const float* __restrict__ el, const float* __restrict__ er,
    const float* __restrict__ cs, const float* __restrict__ cd,
    float* __restrict__ w) {
  int t = blockIdx.x * blockDim.x + threadIdx.x;
  if (t >= N_NODES * 4) return;
  int d = t >> 2, h = t & 3;
  float er_d = er[d * 4 + h];
  float cdv = cd[t];
  int beg = row_ptr[d], end = row_ptr[d + 1];
  for (int p = beg; p < end; ++p) {
    int s_ = col[p];
    float e = lrelu(el[s_ * 4 + h] + er_d);
    w[(size_t)p * 4 + h] = __expf(e - cdv - cs[s_ * 4 + h]);
  }
}

// -------- one hop: wave per dst node, lane = 4 consecutive feats (float4) ----
__global__ __launch_bounds__(256) void hop_kernel(
    const float* __restrict__ xin, float* __restrict__ xout,
    const int* __restrict__ row_ptr, const int* __restrict__ col,
    const float* __restrict__ w, const float* __restrict__ norm_in) {
  int wave = (int)(((size_t)blockIdx.x * blockDim.x + threadIdx.x) >> 6);
  int lane = threadIdx.x & 63;
  if (wave >= N_NODES) return;
  int d = wave;
  int hh = lane >> 4;                       // head owning this lane's 4 floats
  int beg = row_ptr[d], end = row_ptr[d + 1];
  float4 acc = make_float4(0.f, 0.f, 0.f, 0.f);
  for (int p = beg; p < end; ++p) {
    int s = col[p];
    float wt = w[(size_t)p * 4 + hh];       // 16-lane broadcast load
    float4 xv = *(const float4*)&xin[(size_t)s * HF + lane * 4];
    acc.x = fmaf(wt, xv.x, acc.x);
    acc.y = fmaf(wt, xv.y, acc.y);
    acc.z = fmaf(wt, xv.z, acc.z);
    acc.w = fmaf(wt, xv.w, acc.w);
  }
  float ni = norm_in[d];
  acc.x *= ni; acc.y *= ni; acc.z *= ni; acc.w *= ni;
  *(float4*)&xout[(size_t)d * HF + lane * 4] = acc;
}

// -------- hop-attention softmax over {h, x1, x2, x3} + combine ---------------
__global__ __launch_bounds__(256) void final_combine(
    const float* __restrict__ h0, const float* __restrict__ x1,
    const float* __restrict__ x2, const float* __restrict__ x3,
    const float* __restrict__ al, const float* __restrict__ hop_attn_r,
    float* __restrict__ out) {
  int n = blockIdx.x, t = threadIdx.x;
  size_t idx = (size_t)n * HF + t;
  float v0 = h0[idx], v1 = x1[idx], v2 = x2[idx], v3 = x3[idx];
  float wr = hop_attn_r[t];
  float b0 = v0 * wr, b1 = v1 * wr, b2 = v2 * wr, b3 = v3 * wr;
#pragma unroll
  for (int off = 32; off; off >>= 1) {
    b0 += __shfl_xor(b0, off);
    b1 += __shfl_xor(b1, off);
    b2 += __shfl_xor(b2, off);
    b3 += __shfl_xor(b3, off);
  }
  float a0 = al[n * 4 + (t >> 6)];
  b0 = lrelu(b0 + a0); b1 = lrelu(b1 + a0); b2 = lrelu(b2 + a0); b3 = lrelu(b3 + a0);
  float m = fmaxf(fmaxf(b0, b1), fmaxf(b2, b3));
  float e0 = expf(b0 - m), e1 = expf(b1 - m), e2 = expf(b2 - m), e3 = expf(b3 - m);
  float inv = 1.f / (e0 + e1 + e2 + e3);
  out[idx] = (v0 * e0 + v1 * e1 + v2 * e2 + v3 * e3) * inv;
}

extern "C" void kernel_launch(void* const* d_in, const int* in_sizes, int n_in,
                              void* d_out, int out_size, void* d_ws, size_t ws_size,
                              hipStream_t stream) {
  const float* feat       = (const float*)d_in[0];
  const int*   src        = (const int*)d_in[1];
  const int*   dst        = (const int*)d_in[2];
  const float* W          = (const float*)d_in[3];
  const float* attn_l     = (const float*)d_in[4];
  const float* attn_r     = (const float*)d_in[5];
  const float* hop_attn_l = (const float*)d_in[6];
  const float* hop_attn_r = (const float*)d_in[7];
  const float* sigma      = (const float*)d_in[8];
  float* out = (float*)d_out;

  char* ws = (char*)d_ws;
  size_t off = 0;
  auto alloc = [&](size_t bytes) -> void* {
    void* p = ws + off;
    off = align256(off + bytes);
    return p;
  };
  float* hbuf   = (float*)alloc((size_t)N_NODES * HF * 4);   // hop 0
  float* x1     = (float*)alloc((size_t)N_NODES * HF * 4);   // hop 1 (recA early)
  float* x2     = (float*)alloc((size_t)N_NODES * HF * 4);   // hop 2 (recB early)
  float* w_csr  = (float*)alloc((size_t)N_EDGES * 4 * 4);    // CSR edge weights [pos][h]
  int*   col    = (int*)alloc((size_t)N_EDGES * 4);          // CSR payload: src
  int*   row    = (int*)alloc((size_t)N_EDGES * 4);          // CSC payload: dst
  int*   row_ptr= (int*)alloc((size_t)(N_NODES + 1) * 4);
  int*   col_ptr= (int*)alloc((size_t)(N_NODES + 1) * 4);
  float* el     = (float*)alloc((size_t)N_NODES * 4 * 4);
  float* er     = (float*)alloc((size_t)N_NODES * 4 * 4);
  float* al     = (float*)alloc((size_t)N_NODES * 4 * 4);
  float* cs     = (float*)alloc((size_t)N_NODES * 4 * 4);
  float* cd     = (float*)alloc((size_t)N_NODES * 4 * 4);
  float* norm_in= (float*)alloc((size_t)N_NODES * 4);
  int* baseA    = (int*)alloc((size_t)(NBINS + 1) * 4);
  int* baseB    = (int*)alloc((size_t)(NBINS + 1) * 4);
  int* allocA   = (int*)alloc((size_t)NBINS * 4);
  int* allocB   = (int*)alloc((size_t)NBINS * 4);
  size_t zoff = off;
  int* binA     = (int*)alloc((size_t)NBINS * 4);
  int* binB     = (int*)alloc((size_t)NBINS * 4);
  size_t zbytes = off - zoff;
  // edge-record staging aliases hop buffers (dead before hops run)
  int2* recA = (int2*)x1;
  int2* recB = (int2*)x2;

  hipMemsetAsync(ws + zoff, 0, zbytes, stream);

  // h = feat @ W
  gemm_kernel<<<dim3((N_NODES + 127) / 128, 2), 256, 0, stream>>>(feat, W, hbuf);
  node_dots<<<N_NODES, 256, 0, stream>>>(hbuf, attn_l, attn_r, hop_attn_l, el, er, al);
  // CSR/CSC build via two-level counting sort (no random scatter to HBM)
  const int EB = N_EDGES / 256;  // exactly 3125
  bin_hist<<<EB, 256, 0, stream>>>(src, dst, binA, binB);
  bin_scan<<<1, 64, 0, stream>>>(binA, binB, baseA, baseB, allocA, allocB, row_ptr, col_ptr);
  bin_scatter<<<EB, 256, 0, stream>>>(src, dst, allocA, allocB, recA, recB);
  bin_sort<<<dim3(NBINS, 2), 256, 0, stream>>>(recA, baseA, row_ptr, col,
                                               recB, baseB, col_ptr, row);
  norm_in_kernel<<<(N_NODES + 255) / 256, 256, 0, stream>>>(row_ptr, norm_in);
  // softmax log-coefficients (node-centric, no atomics, no max pass)
  const int NT = (N_NODES * 4 + 255) / 256;
  seg_stats<<<NT, 256, 0, stream>>>(row_ptr, col, er, el, sigma, 0, cd);  // dst-grouped
  seg_stats<<<NT, 256, 0, stream>>>(col_ptr, row, el, er, sigma, 1, cs);  // src-grouped
  // per-edge weights (one exp each), CSR order
  csr_weights<<<NT, 256, 0, stream>>>(row_ptr, col, el, er, cs, cd, w_csr);
  // K = 3 hops
  const int HB = (N_NODES * 64 + 255) / 256;
  hop_kernel<<<HB, 256, 0, stream>>>(hbuf, x1, row_ptr, col, w_csr, norm_in);
  hop_kernel<<<HB, 256, 0, stream>>>(x1, x2, row_ptr, col, w_csr, norm_in);
  hop_kernel<<<HB, 256, 0, stream>>>(x2, out, row_ptr, col, w_csr, norm_in);
  // hop-attention combine
  final_combine<<<N_NODES, 256, 0, stream>>>(hbuf, x1, x2, out, al, hop_attn_r, out);
}

// Round 4
// 787.204 us; speedup vs baseline: 1.7687x; 1.1039x over previous
//
#include <hip/hip_runtime.h>
#include <hip/hip_bf16.h>

#define N_NODES 50000
#define N_EDGES 800000
#define HF      256   // H_HEADS * F_OUT
#define SLOPE   0.2f
#define BIN_W   1024
#define NBINS   49    // ceil(N_NODES / BIN_W)

static inline size_t align256(size_t x) { return (x + 255) & ~(size_t)255; }

__device__ __forceinline__ float lrelu(float x) { return x > 0.f ? x : SLOPE * x; }

// exact bf16 -> f32 widening
__device__ __forceinline__ float bf2f(unsigned short b) {
  return __uint_as_float(((unsigned)b) << 16);
}
// f32 -> bf16 with round-to-nearest-even
__device__ __forceinline__ unsigned short f2bf(float f) {
  unsigned u = __float_as_uint(f);
  unsigned r = (u + 0x7FFFu + ((u >> 16) & 1u)) >> 16;
  return (unsigned short)r;
}

// ---------------- GEMM: h = feat(50000x256) @ W(256x256), f32 ----------------
__global__ __launch_bounds__(256) void gemm_kernel(
    const float* __restrict__ A, const float* __restrict__ B, float* __restrict__ C) {
  __shared__ float As[16][132];
  __shared__ float Bs[16][128];
  int tid = threadIdx.x;
  int bm = blockIdx.x * 128, bn = blockIdx.y * 128;
  int tx = tid & 15, ty = tid >> 4;
  float acc[8][8];
#pragma unroll
  for (int i = 0; i < 8; ++i)
#pragma unroll
    for (int j = 0; j < 8; ++j) acc[i][j] = 0.f;

  int la_r = (tid * 8) >> 4;
  int la_k = (tid * 8) & 15;
  int lb_k = (tid * 8) >> 7;
  int lb_c = (tid * 8) & 127;

  for (int k0 = 0; k0 < 256; k0 += 16) {
    float4 va0, va1;
    int gr = bm + la_r;
    if (gr < N_NODES) {
      const float* ap = A + (size_t)gr * 256 + k0 + la_k;
      va0 = *(const float4*)ap; va1 = *(const float4*)(ap + 4);
    } else {
      va0 = make_float4(0, 0, 0, 0); va1 = va0;
    }
    As[la_k + 0][la_r] = va0.x; As[la_k + 1][la_r] = va0.y;
    As[la_k + 2][la_r] = va0.z; As[la_k + 3][la_r] = va0.w;
    As[la_k + 4][la_r] = va1.x; As[la_k + 5][la_r] = va1.y;
    As[la_k + 6][la_r] = va1.z; As[la_k + 7][la_r] = va1.w;

    const float* bp = B + (size_t)(k0 + lb_k) * 256 + bn + lb_c;
    float4 vb0 = *(const float4*)bp, vb1 = *(const float4*)(bp + 4);
    *(float4*)&Bs[lb_k][lb_c] = vb0; *(float4*)&Bs[lb_k][lb_c + 4] = vb1;
    __syncthreads();
#pragma unroll
    for (int kk = 0; kk < 16; ++kk) {
      float a[8], b[8];
#pragma unroll
      for (int i = 0; i < 8; ++i) a[i] = As[kk][ty * 8 + i];
#pragma unroll
      for (int j = 0; j < 8; ++j) b[j] = Bs[kk][tx * 8 + j];
#pragma unroll
      for (int i = 0; i < 8; ++i)
#pragma unroll
        for (int j = 0; j < 8; ++j) acc[i][j] = fmaf(a[i], b[j], acc[i][j]);
    }
    __syncthreads();
  }
#pragma unroll
  for (int i = 0; i < 8; ++i) {
    int r = bm + ty * 8 + i;
    if (r < N_NODES) {
      float4* cp = (float4*)(C + (size_t)r * 256 + bn + tx * 8);
      cp[0] = make_float4(acc[i][0], acc[i][1], acc[i][2], acc[i][3]);
      cp[1] = make_float4(acc[i][4], acc[i][5], acc[i][6], acc[i][7]);
    }
  }
}

// ------- per-node dots: el, er, al + bf16 copy of h --------------------------
__global__ __launch_bounds__(256) void node_dots(
    const float* __restrict__ hbuf, const float* __restrict__ attn_l,
    const float* __restrict__ attn_r, const float* __restrict__ hop_attn_l,
    float* __restrict__ el, float* __restrict__ er, float* __restrict__ al,
    unsigned short* __restrict__ h_bf) {
  int n = blockIdx.x, t = threadIdx.x;
  int hh = t >> 6, f = t & 63;
  size_t idx = (size_t)n * HF + t;
  float x = hbuf[idx];
  h_bf[idx] = f2bf(x);
  float pl = x * attn_l[t], pr = x * attn_r[t], pa = x * hop_attn_l[t];
#pragma unroll
  for (int off = 32; off; off >>= 1) {
    pl += __shfl_xor(pl, off);
    pr += __shfl_xor(pr, off);
    pa += __shfl_xor(pa, off);
  }
  if (f == 0) {
    el[n * 4 + hh] = pl; er[n * 4 + hh] = pr; al[n * 4 + hh] = pa;
  }
}

// -------- pass A: per-bin edge histograms (LDS-aggregated) -------------------
__global__ __launch_bounds__(256) void bin_hist(
    const int* __restrict__ src, const int* __restrict__ dst,
    int* __restrict__ binA, int* __restrict__ binB) {
  __shared__ int cA[NBINS], cB[NBINS];
  int t = threadIdx.x;
  if (t < NBINS) { cA[t] = 0; cB[t] = 0; }
  __syncthreads();
  int e = blockIdx.x * 256 + t;            // grid covers exactly N_EDGES
  int s = src[e], d = dst[e];
  atomicAdd(&cA[d >> 10], 1);
  atomicAdd(&cB[s >> 10], 1);
  __syncthreads();
  if (t < NBINS) {
    if (cA[t]) atomicAdd(&binA[t], cA[t]);
    if (cB[t]) atomicAdd(&binB[t], cB[t]);
  }
}

// -------- pass B: scan bin counts -> bases + alloc cursors -------------------
__global__ void bin_scan(const int* __restrict__ binA, const int* __restrict__ binB,
                         int* __restrict__ baseA, int* __restrict__ baseB,
                         int* __restrict__ allocA, int* __restrict__ allocB,
                         int* __restrict__ row_ptr, int* __restrict__ col_ptr) {
  int t = threadIdx.x;  // 64 threads, one wave
  int vA = (t < NBINS) ? binA[t] : 0;
  int vB = (t < NBINS) ? binB[t] : 0;
  int xA = vA, xB = vB;
#pragma unroll
  for (int off = 1; off < 64; off <<= 1) {
    int yA = __shfl_up(xA, off);
    int yB = __shfl_up(xB, off);
    if (t >= off) { xA += yA; xB += yB; }
  }
  if (t < NBINS) {
    baseA[t] = xA - vA; allocA[t] = xA - vA;
    baseB[t] = xB - vB; allocB[t] = xB - vB;
  }
  if (t == NBINS - 1) {
    baseA[NBINS] = xA; baseB[NBINS] = xB;
    row_ptr[N_NODES] = N_EDGES; col_ptr[N_NODES] = N_EDGES;
  }
}

// -------- pass C: chunked binning of 8B edge records -------------------------
__global__ __launch_bounds__(256) void bin_scatter(
    const int* __restrict__ src, const int* __restrict__ dst,
    int* __restrict__ allocA, int* __restrict__ allocB,
    int2* __restrict__ recA, int2* __restrict__ recB) {
  __shared__ int cA[NBINS], cB[NBINS], bA[NBINS], bB[NBINS];
  int t = threadIdx.x;
  if (t < NBINS) { cA[t] = 0; cB[t] = 0; }
  __syncthreads();
  int e = blockIdx.x * 256 + t;
  int s = src[e], d = dst[e];
  int ba = d >> 10, bb = s >> 10;
  int ra = atomicAdd(&cA[ba], 1);
  int rb = atomicAdd(&cB[bb], 1);
  __syncthreads();
  if (t < NBINS) {
    bA[t] = cA[t] ? atomicAdd(&allocA[t], cA[t]) : 0;
    bB[t] = cB[t] ? atomicAdd(&allocB[t], cB[t]) : 0;
  }
  __syncthreads();
  recA[bA[ba] + ra] = make_int2(s, d);  // payload=src, key=dst
  recB[bB[bb] + rb] = make_int2(d, s);  // payload=dst, key=src
}

// -------- pass D: in-LDS counting sort per bin -> ptr + payload arrays -------
__global__ __launch_bounds__(256) void bin_sort(
    const int2* __restrict__ recA, const int* __restrict__ baseA,
    int* __restrict__ row_ptr, int* __restrict__ outA,
    const int2* __restrict__ recB, const int* __restrict__ baseB,
    int* __restrict__ col_ptr, int* __restrict__ outB) {
  const int2* rec; const int* base; int* ptr; int* out;
  if (blockIdx.y == 0) { rec = recA; base = baseA; ptr = row_ptr; out = outA; }
  else                 { rec = recB; base = baseB; ptr = col_ptr; out = outB; }
  __shared__ int hist[BIN_W];
  __shared__ int wsum[4];
  int b = blockIdx.x, t = threadIdx.x;
  int n0 = b << 10;
  int nn = min(BIN_W, N_NODES - n0);
  int beg = base[b], end = base[b + 1];
  for (int i = t; i < BIN_W; i += 256) hist[i] = 0;
  __syncthreads();
  for (int p = beg + t; p < end; p += 256)
    atomicAdd(&hist[rec[p].y - n0], 1);
  __syncthreads();
  int i0 = t * 4;
  int h0 = hist[i0], h1 = hist[i0 + 1], h2 = hist[i0 + 2], h3 = hist[i0 + 3];
  int sum4 = h0 + h1 + h2 + h3;
  int x = sum4;
  int lane = t & 63, wid = t >> 6;
#pragma unroll
  for (int off = 1; off < 64; off <<= 1) {
    int y = __shfl_up(x, off);
    if (lane >= off) x += y;
  }
  if (lane == 63) wsum[wid] = x;
  __syncthreads();
  int wpre = 0;
#pragma unroll
  for (int wj = 0; wj < 4; ++wj) wpre += (wj < wid) ? wsum[wj] : 0;
  int excl = wpre + x - sum4;            // exclusive prefix of this 4-group
  int e0 = excl, e1 = excl + h0, e2 = excl + h0 + h1, e3 = excl + h0 + h1 + h2;
  hist[i0] = e0; hist[i0 + 1] = e1; hist[i0 + 2] = e2; hist[i0 + 3] = e3;
  if (i0 + 0 < nn) ptr[n0 + i0 + 0] = beg + e0;
  if (i0 + 1 < nn) ptr[n0 + i0 + 1] = beg + e1;
  if (i0 + 2 < nn) ptr[n0 + i0 + 2] = beg + e2;
  if (i0 + 3 < nn) ptr[n0 + i0 + 3] = beg + e3;
  __syncthreads();
  for (int p = beg + t; p < end; p += 256) {
    int2 r = rec[p];
    int pos = atomicAdd(&hist[r.y - n0], 1);
    out[beg + pos] = r.x;
  }
}

// ---------------- norm_in from row_ptr diffs ---------------------------------
__global__ void norm_in_kernel(const int* __restrict__ row_ptr, float* __restrict__ norm_in) {
  int n = blockIdx.x * blockDim.x + threadIdx.x;
  if (n >= N_NODES) return;
  int deg = row_ptr[n + 1] - row_ptr[n];
  norm_in[n] = sqrtf((float)max(deg, 1));
}

// ---- per-(src,head): cs = (1-sg)*ln(S_src) + 0.5*ln(outdeg) [folds norm_out]
__global__ __launch_bounds__(256) void src_coef(
    const int* __restrict__ col_ptr, const int* __restrict__ row,
    const float* __restrict__ el, const float* __restrict__ er,
    const float* __restrict__ sigma, float* __restrict__ cs) {
  int t = blockIdx.x * blockDim.x + threadIdx.x;
  if (t >= N_NODES * 4) return;
  int n = t >> 2, h = t & 3;
  float sg = 1.f / (1.f + __expf(-sigma[0]));
  float o = el[n * 4 + h];
  int beg = col_ptr[n], end = col_ptr[n + 1];
  float s = 0.f;
  for (int p = beg; p < end; ++p) {
    int u = row[p];
    s += __expf(lrelu(er[u * 4 + h] + o));
  }
  cs[t] = (1.f - sg) * __logf(s) + 0.5f * __logf((float)max(end - beg, 1));
}

// ---- per-(dst,head): S_d inline, then w = exp(e - sg*lnS_d - cs[src]) -------
__global__ __launch_bounds__(256) void csr_weights(
    const int* __restrict__ row_ptr, const int* __restrict__ col,
    const float* __restrict__ el, const float* __restrict__ er,
    const float* __restrict__ cs, const float* __restrict__ sigma,
    float* __restrict__ w) {
  int t = blockIdx.x * blockDim.x + threadIdx.x;
  if (t >= N_NODES * 4) return;
  int d = t >> 2, h = t & 3;
  float sg = 1.f / (1.f + __expf(-sigma[0]));
  float er_d = er[d * 4 + h];
  int beg = row_ptr[d], end = row_ptr[d + 1];
  float S = 0.f;
  for (int p = beg; p < end; ++p) {
    int s_ = col[p];
    S += __expf(lrelu(el[s_ * 4 + h] + er_d));
  }
  float cdv = sg * __logf(S);
  for (int p = beg; p < end; ++p) {
    int s_ = col[p];
    float e = lrelu(el[s_ * 4 + h] + er_d);
    w[(size_t)p * 4 + h] = __expf(e - cdv - cs[s_ * 4 + h]);
  }
}

// -------- one hop: wave per dst node, bf16 in / bf16 out ---------------------
__global__ __launch_bounds__(256) void hop_kernel(
    const unsigned short* __restrict__ xin, unsigned short* __restrict__ xout,
    const int* __restrict__ row_ptr, const int* __restrict__ col,
    const float* __restrict__ w, const float* __restrict__ norm_in) {
  int wave = (int)(((size_t)blockIdx.x * blockDim.x + threadIdx.x) >> 6);
  int lane = threadIdx.x & 63;
  if (wave >= N_NODES) return;
  int d = wave;
  int hh = lane >> 4;                       // head owning this lane's 4 elems
  int beg = row_ptr[d], end = row_ptr[d + 1];
  float a0 = 0.f, a1 = 0.f, a2 = 0.f, a3 = 0.f;
  for (int p = beg; p < end; ++p) {
    int s = col[p];
    float wt = w[(size_t)p * 4 + hh];
    ushort4 u = *(const ushort4*)&xin[(size_t)s * HF + lane * 4];
    a0 = fmaf(wt, bf2f(u.x), a0);
    a1 = fmaf(wt, bf2f(u.y), a1);
    a2 = fmaf(wt, bf2f(u.z), a2);
    a3 = fmaf(wt, bf2f(u.w), a3);
  }
  float ni = norm_in[d];
  ushort4 o;
  o.x = f2bf(a0 * ni); o.y = f2bf(a1 * ni);
  o.z = f2bf(a2 * ni); o.w = f2bf(a3 * ni);
  *(ushort4*)&xout[(size_t)d * HF + lane * 4] = o;
}

// -------- hop-attention softmax over {h, x1, x2, x3} + combine ---------------
__global__ __launch_bounds__(256) void final_combine(
    const float* __restrict__ h0, const unsigned short* __restrict__ x1,
    const unsigned short* __restrict__ x2, const unsigned short* __restrict__ x3,
    const float* __restrict__ al, const float* __restrict__ hop_attn_r,
    float* __restrict__ out) {
  int n = blockIdx.x, t = threadIdx.x;
  size_t idx = (size_t)n * HF + t;
  float v0 = h0[idx], v1 = bf2f(x1[idx]), v2 = bf2f(x2[idx]), v3 = bf2f(x3[idx]);
  float wr = hop_attn_r[t];
  float b0 = v0 * wr, b1 = v1 * wr, b2 = v2 * wr, b3 = v3 * wr;
#pragma unroll
  for (int off = 32; off; off >>= 1) {
    b0 += __shfl_xor(b0, off);
    b1 += __shfl_xor(b1, off);
    b2 += __shfl_xor(b2, off);
    b3 += __shfl_xor(b3, off);
  }
  float a0 = al[n * 4 + (t >> 6)];
  b0 = lrelu(b0 + a0); b1 = lrelu(b1 + a0); b2 = lrelu(b2 + a0); b3 = lrelu(b3 + a0);
  float m = fmaxf(fmaxf(b0, b1), fmaxf(b2, b3));
  float e0 = expf(b0 - m), e1 = expf(b1 - m), e2 = expf(b2 - m), e3 = expf(b3 - m);
  float inv = 1.f / (e0 + e1 + e2 + e3);
  out[idx] = (v0 * e0 + v1 * e1 + v2 * e2 + v3 * e3) * inv;
}

extern "C" void kernel_launch(void* const* d_in, const int* in_sizes, int n_in,
                              void* d_out, int out_size, void* d_ws, size_t ws_size,
                              hipStream_t stream) {
  const float* feat       = (const float*)d_in[0];
  const int*   src        = (const int*)d_in[1];
  const int*   dst        = (const int*)d_in[2];
  const float* W          = (const float*)d_in[3];
  const float* attn_l     = (const float*)d_in[4];
  const float* attn_r     = (const float*)d_in[5];
  const float* hop_attn_l = (const float*)d_in[6];
  const float* hop_attn_r = (const float*)d_in[7];
  const float* sigma      = (const float*)d_in[8];
  float* out = (float*)d_out;

  char* ws = (char*)d_ws;
  size_t off = 0;
  auto alloc = [&](size_t bytes) -> void* {
    void* p = ws + off;
    off = align256(off + bytes);
    return p;
  };
  float*          hbuf  = (float*)alloc((size_t)N_NODES * HF * 4);          // h, f32
  unsigned short* h_bf  = (unsigned short*)alloc((size_t)N_NODES * HF * 2); // h, bf16
  unsigned short* x1    = (unsigned short*)alloc((size_t)N_NODES * HF * 2); // hop1 bf16
  unsigned short* x2    = (unsigned short*)alloc((size_t)N_NODES * HF * 2); // hop2 bf16
  unsigned short* x3    = (unsigned short*)alloc((size_t)N_NODES * HF * 2); // hop3 bf16
  float* w_csr  = (float*)alloc((size_t)N_EDGES * 4 * 4);    // CSR edge weights [pos][h]
  int*   col    = (int*)alloc((size_t)N_EDGES * 4);          // CSR payload: src
  int*   row    = (int*)alloc((size_t)N_EDGES * 4);          // CSC payload: dst
  int*   row_ptr= (int*)alloc((size_t)(N_NODES + 1) * 4);
  int*   col_ptr= (int*)alloc((size_t)(N_NODES + 1) * 4);
  float* el     = (float*)alloc((size_t)N_NODES * 4 * 4);
  float* er     = (float*)alloc((size_t)N_NODES * 4 * 4);
  float* al     = (float*)alloc((size_t)N_NODES * 4 * 4);
  float* cs     = (float*)alloc((size_t)N_NODES * 4 * 4);
  float* norm_in= (float*)alloc((size_t)N_NODES * 4);
  int* baseA    = (int*)alloc((size_t)(NBINS + 1) * 4);
  int* baseB    = (int*)alloc((size_t)(NBINS + 1) * 4);
  int* allocA   = (int*)alloc((size_t)NBINS * 4);
  int* allocB   = (int*)alloc((size_t)NBINS * 4);
  size_t zoff = off;
  int* binA     = (int*)alloc((size_t)NBINS * 4);
  int* binB     = (int*)alloc((size_t)NBINS * 4);
  size_t zbytes = off - zoff;
  // edge-record staging aliases bf16 hop buffers (dead before hops run)
  int2* recA = (int2*)x1;   // 6.4MB <= 25.6MB region
  int2* recB = (int2*)x2;

  hipMemsetAsync(ws + zoff, 0, zbytes, stream);

  // h = feat @ W
  gemm_kernel<<<dim3((N_NODES + 127) / 128, 2), 256, 0, stream>>>(feat, W, hbuf);
  node_dots<<<N_NODES, 256, 0, stream>>>(hbuf, attn_l, attn_r, hop_attn_l, el, er, al, h_bf);
  // CSR/CSC build via two-level counting sort (no random scatter to HBM)
  const int EB = N_EDGES / 256;  // exactly 3125
  bin_hist<<<EB, 256, 0, stream>>>(src, dst, binA, binB);
  bin_scan<<<1, 64, 0, stream>>>(binA, binB, baseA, baseB, allocA, allocB, row_ptr, col_ptr);
  bin_scatter<<<EB, 256, 0, stream>>>(src, dst, allocA, allocB, recA, recB);
  bin_sort<<<dim3(NBINS, 2), 256, 0, stream>>>(recA, baseA, row_ptr, col,
                                               recB, baseB, col_ptr, row);
  norm_in_kernel<<<(N_NODES + 255) / 256, 256, 0, stream>>>(row_ptr, norm_in);
  // softmax log-coefficients + per-edge weights (node-centric, no atomics)
  const int NT = (N_NODES * 4 + 255) / 256;
  src_coef<<<NT, 256, 0, stream>>>(col_ptr, row, el, er, sigma, cs);
  csr_weights<<<NT, 256, 0, stream>>>(row_ptr, col, el, er, cs, sigma, w_csr);
  // K = 3 hops (bf16 gathers)
  const int HB = (N_NODES * 64 + 255) / 256;
  hop_kernel<<<HB, 256, 0, stream>>>(h_bf, x1, row_ptr, col, w_csr, norm_in);
  hop_kernel<<<HB, 256, 0, stream>>>(x1, x2, row_ptr, col, w_csr, norm_in);
  hop_kernel<<<HB, 256, 0, stream>>>(x2, x3, row_ptr, col, w_csr, norm_in);
  // hop-attention combine (f32 h + bf16 hops)
  final_combine<<<N_NODES, 256, 0, stream>>>(hbuf, x1, x2, x3, al, hop_attn_r, out);
}

// Round 5
// 714.483 us; speedup vs baseline: 1.9487x; 1.1018x over previous
//
#include <hip/hip_runtime.h>
#include <hip/hip_bf16.h>

#define N_NODES 50000
#define N_EDGES 800000
#define HF      256   // H_HEADS * F_OUT
#define SLOPE   0.2f
#define BIN_W   1024
#define NBINS   49    // ceil(N_NODES / BIN_W)

static inline size_t align256(size_t x) { return (x + 255) & ~(size_t)255; }

__device__ __forceinline__ float lrelu(float x) { return x > 0.f ? x : SLOPE * x; }

// exact bf16 -> f32 widening
__device__ __forceinline__ float bf2f(unsigned short b) {
  return __uint_as_float(((unsigned)b) << 16);
}
// f32 -> bf16 with round-to-nearest-even
__device__ __forceinline__ unsigned short f2bf(float f) {
  unsigned u = __float_as_uint(f);
  unsigned r = (u + 0x7FFFu + ((u >> 16) & 1u)) >> 16;
  return (unsigned short)r;
}

using f32x4 = __attribute__((ext_vector_type(4))) float;
using s16x8 = __attribute__((ext_vector_type(8))) short;  // 8 bf16 (4 VGPRs)

// ---- W pre-swizzle: f32 W[k][col] -> bf16 fragments [chunk][tile][lane][j] --
// chunk = k>>5, kin = k&31, tile = col>>4, lane = (kin>>3)*16 + (col&15), j = kin&7
__global__ __launch_bounds__(256) void w_swizzle(
    const float* __restrict__ W, unsigned short* __restrict__ W_swz) {
  int t = blockIdx.x * 256 + threadIdx.x;   // 0..65535
  int k = t >> 8, col = t & 255;
  int kin = k & 31, chunk = k >> 5;
  int tile = col >> 4;
  int lane = ((kin >> 3) << 4) | (col & 15);
  int j = kin & 7;
  W_swz[(((chunk * 16 + tile) * 64 + lane) << 3) + j] = f2bf(W[t]);
}

// ---- MFMA GEMM h = feat @ W (bf16 in, f32 acc) + fused el/er/al dots --------
// block = 256 thr (4 waves), BM = 64 rows, BN = 256 (full), K = 256 in 8 chunks
__global__ __launch_bounds__(256) void mfma_gemm(
    const float* __restrict__ feat, const unsigned short* __restrict__ W_swz,
    float* __restrict__ hbuf, unsigned short* __restrict__ h_bf,
    const float* __restrict__ attn_l, const float* __restrict__ attn_r,
    const float* __restrict__ hop_attn_l,
    float* __restrict__ el, float* __restrict__ er, float* __restrict__ al) {
  __shared__ unsigned short sW[32768];      // 64KB: one K-half of fragments
  int tid = threadIdx.x;
  int w = tid >> 6, lane = tid & 63;
  int c15 = lane & 15, g = lane >> 4;
  int wave_row = blockIdx.x * 64 + w * 16;  // 16 rows per wave
  int row_a = wave_row + c15;               // A-fragment row for this lane
  bool va = row_a < N_NODES;

  // issue ALL A loads up front (64 f32/lane = row_a, k = chunk*32 + g*8 + 0..7)
  float4 av[16];
  const float* ap = feat + (size_t)row_a * 256 + g * 8;
#pragma unroll
  for (int c = 0; c < 8; ++c) {
    if (va) {
      av[2 * c]     = *(const float4*)(ap + c * 32);
      av[2 * c + 1] = *(const float4*)(ap + c * 32 + 4);
    } else {
      av[2 * c] = make_float4(0.f, 0.f, 0.f, 0.f);
      av[2 * c + 1] = av[2 * c];
    }
  }

  f32x4 acc[16];
#pragma unroll
  for (int t = 0; t < 16; ++t) acc[t] = (f32x4){0.f, 0.f, 0.f, 0.f};

  const s16x8* sWf = (const s16x8*)sW;
#pragma unroll
  for (int hf = 0; hf < 2; ++hf) {
    // stage K-half of pre-swizzled W: pure linear copy
    if (hf) __syncthreads();                 // waves done reading previous half
    {
      const uint4* gw = (const uint4*)(W_swz + hf * 32768);
      uint4* sw4 = (uint4*)sW;
      for (int i = tid; i < 4096; i += 256) sw4[i] = gw[i];
    }
    __syncthreads();
#pragma unroll
    for (int cc = 0; cc < 4; ++cc) {
      int c = hf * 4 + cc;
      // convert this chunk's A to bf16 fragment
      s16x8 a;
      const float* p0 = (const float*)&av[2 * c];
#pragma unroll
      for (int j = 0; j < 8; ++j) a[j] = (short)f2bf(p0[j]);
#pragma unroll
      for (int t = 0; t < 16; ++t) {
        s16x8 b = sWf[(cc * 16 + t) * 64 + lane];
        acc[t] = __builtin_amdgcn_mfma_f32_16x16x32_bf16(a, b, acc[t], 0, 0, 0);
      }
    }
  }

  // ---- fused epilogue ----
  // dots: partial per (r, h) over this lane's 16 cols  (pl[r*4+h])
  float pl[16], pr[16], pa[16];
#pragma unroll
  for (int i = 0; i < 16; ++i) { pl[i] = 0.f; pr[i] = 0.f; pa[i] = 0.f; }
#pragma unroll
  for (int t = 0; t < 16; ++t) {
    int colv = t * 16 + c15;
    float la = attn_l[colv], ra = attn_r[colv], ha = hop_attn_l[colv];
    int h = t >> 2;
#pragma unroll
    for (int r = 0; r < 4; ++r) {
      pl[r * 4 + h] = fmaf(acc[t][r], la, pl[r * 4 + h]);
      pr[r * 4 + h] = fmaf(acc[t][r], ra, pr[r * 4 + h]);
      pa[r * 4 + h] = fmaf(acc[t][r], ha, pa[r * 4 + h]);
    }
  }
  // reduce across the 16 lanes of this lane-group (rows identical within group)
#pragma unroll
  for (int i = 0; i < 16; ++i) {
#pragma unroll
    for (int off = 8; off; off >>= 1) {
      pl[i] += __shfl_xor(pl[i], off);
      pr[i] += __shfl_xor(pr[i], off);
      pa[i] += __shfl_xor(pa[i], off);
    }
  }
  int rowg = wave_row + g * 4;              // this group's 4 rows
  if (c15 == 0) {
#pragma unroll
    for (int r = 0; r < 4; ++r) {
      if (rowg + r < N_NODES) {
        *(float4*)&el[(rowg + r) * 4] = make_float4(pl[r*4+0], pl[r*4+1], pl[r*4+2], pl[r*4+3]);
        *(float4*)&er[(rowg + r) * 4] = make_float4(pr[r*4+0], pr[r*4+1], pr[r*4+2], pr[r*4+3]);
        *(float4*)&al[(rowg + r) * 4] = make_float4(pa[r*4+0], pa[r*4+1], pa[r*4+2], pa[r*4+3]);
      }
    }
  }
  // store h (f32) and h_bf (bf16)
#pragma unroll
  for (int r = 0; r < 4; ++r) {
    int row = rowg + r;
    if (row < N_NODES) {
#pragma unroll
      for (int t = 0; t < 16; ++t) {
        float v = acc[t][r];
        size_t o = (size_t)row * HF + t * 16 + c15;
        hbuf[o] = v;
        h_bf[o] = f2bf(v);
      }
    }
  }
}

// -------- pass A: per-bin edge histograms (LDS-aggregated) -------------------
__global__ __launch_bounds__(256) void bin_hist(
    const int* __restrict__ src, const int* __restrict__ dst,
    int* __restrict__ binA, int* __restrict__ binB) {
  __shared__ int cA[NBINS], cB[NBINS];
  int t = threadIdx.x;
  if (t < NBINS) { cA[t] = 0; cB[t] = 0; }
  __syncthreads();
  int e = blockIdx.x * 256 + t;            // grid covers exactly N_EDGES
  int s = src[e], d = dst[e];
  atomicAdd(&cA[d >> 10], 1);
  atomicAdd(&cB[s >> 10], 1);
  __syncthreads();
  if (t < NBINS) {
    if (cA[t]) atomicAdd(&binA[t], cA[t]);
    if (cB[t]) atomicAdd(&binB[t], cB[t]);
  }
}

// -------- pass B: scan bin counts -> bases + alloc cursors -------------------
__global__ void bin_scan(const int* __restrict__ binA, const int* __restrict__ binB,
                         int* __restrict__ baseA, int* __restrict__ baseB,
                         int* __restrict__ allocA, int* __restrict__ allocB,
                         int* __restrict__ row_ptr, int* __restrict__ col_ptr) {
  int t = threadIdx.x;  // 64 threads, one wave
  int vA = (t < NBINS) ? binA[t] : 0;
  int vB = (t < NBINS) ? binB[t] : 0;
  int xA = vA, xB = vB;
#pragma unroll
  for (int off = 1; off < 64; off <<= 1) {
    int yA = __shfl_up(xA, off);
    int yB = __shfl_up(xB, off);
    if (t >= off) { xA += yA; xB += yB; }
  }
  if (t < NBINS) {
    baseA[t] = xA - vA; allocA[t] = xA - vA;
    baseB[t] = xB - vB; allocB[t] = xB - vB;
  }
  if (t == NBINS - 1) {
    baseA[NBINS] = xA; baseB[NBINS] = xB;
    row_ptr[N_NODES] = N_EDGES; col_ptr[N_NODES] = N_EDGES;
  }
}

// -------- pass C: chunked binning of 8B edge records -------------------------
__global__ __launch_bounds__(256) void bin_scatter(
    const int* __restrict__ src, const int* __restrict__ dst,
    int* __restrict__ allocA, int* __restrict__ allocB,
    int2* __restrict__ recA, int2* __restrict__ recB) {
  __shared__ int cA[NBINS], cB[NBINS], bA[NBINS], bB[NBINS];
  int t = threadIdx.x;
  if (t < NBINS) { cA[t] = 0; cB[t] = 0; }
  __syncthreads();
  int e = blockIdx.x * 256 + t;
  int s = src[e], d = dst[e];
  int ba = d >> 10, bb = s >> 10;
  int ra = atomicAdd(&cA[ba], 1);
  int rb = atomicAdd(&cB[bb], 1);
  __syncthreads();
  if (t < NBINS) {
    bA[t] = cA[t] ? atomicAdd(&allocA[t], cA[t]) : 0;
    bB[t] = cB[t] ? atomicAdd(&allocB[t], cB[t]) : 0;
  }
  __syncthreads();
  recA[bA[ba] + ra] = make_int2(s, d);  // payload=src, key=dst
  recB[bB[bb] + rb] = make_int2(d, s);  // payload=dst, key=src
}

// -------- pass D: in-LDS counting sort per bin -> ptr + payload arrays -------
__global__ __launch_bounds__(256) void bin_sort(
    const int2* __restrict__ recA, const int* __restrict__ baseA,
    int* __restrict__ row_ptr, int* __restrict__ outA,
    const int2* __restrict__ recB, const int* __restrict__ baseB,
    int* __restrict__ col_ptr, int* __restrict__ outB) {
  const int2* rec; const int* base; int* ptr; int* out;
  if (blockIdx.y == 0) { rec = recA; base = baseA; ptr = row_ptr; out = outA; }
  else                 { rec = recB; base = baseB; ptr = col_ptr; out = outB; }
  __shared__ int hist[BIN_W];
  __shared__ int wsum[4];
  int b = blockIdx.x, t = threadIdx.x;
  int n0 = b << 10;
  int nn = min(BIN_W, N_NODES - n0);
  int beg = base[b], end = base[b + 1];
  for (int i = t; i < BIN_W; i += 256) hist[i] = 0;
  __syncthreads();
  for (int p = beg + t; p < end; p += 256)
    atomicAdd(&hist[rec[p].y - n0], 1);
  __syncthreads();
  int i0 = t * 4;
  int h0 = hist[i0], h1 = hist[i0 + 1], h2 = hist[i0 + 2], h3 = hist[i0 + 3];
  int sum4 = h0 + h1 + h2 + h3;
  int x = sum4;
  int lane = t & 63, wid = t >> 6;
#pragma unroll
  for (int off = 1; off < 64; off <<= 1) {
    int y = __shfl_up(x, off);
    if (lane >= off) x += y;
  }
  if (lane == 63) wsum[wid] = x;
  __syncthreads();
  int wpre = 0;
#pragma unroll
  for (int wj = 0; wj < 4; ++wj) wpre += (wj < wid) ? wsum[wj] : 0;
  int excl = wpre + x - sum4;            // exclusive prefix of this 4-group
  int e0 = excl, e1 = excl + h0, e2 = excl + h0 + h1, e3 = excl + h0 + h1 + h2;
  hist[i0] = e0; hist[i0 + 1] = e1; hist[i0 + 2] = e2; hist[i0 + 3] = e3;
  if (i0 + 0 < nn) ptr[n0 + i0 + 0] = beg + e0;
  if (i0 + 1 < nn) ptr[n0 + i0 + 1] = beg + e1;
  if (i0 + 2 < nn) ptr[n0 + i0 + 2] = beg + e2;
  if (i0 + 3 < nn) ptr[n0 + i0 + 3] = beg + e3;
  __syncthreads();
  for (int p = beg + t; p < end; p += 256) {
    int2 r = rec[p];
    int pos = atomicAdd(&hist[r.y - n0], 1);
    out[beg + pos] = r.x;
  }
}

// ---------------- norm_in from row_ptr diffs ---------------------------------
__global__ void norm_in_kernel(const int* __restrict__ row_ptr, float* __restrict__ norm_in) {
  int n = blockIdx.x * blockDim.x + threadIdx.x;
  if (n >= N_NODES) return;
  int deg = row_ptr[n + 1] - row_ptr[n];
  norm_in[n] = sqrtf((float)max(deg, 1));
}

// ---- per-(src,head): cs = (1-sg)*ln(S_src) + 0.5*ln(outdeg) [folds norm_out]
__global__ __launch_bounds__(256) void src_coef(
    const int* __restrict__ col_ptr, const int* __restrict__ row,
    const float* __restrict__ el, const float* __restrict__ er,
    const float* __restrict__ sigma, float* __restrict__ cs) {
  int t = blockIdx.x * blockDim.x + threadIdx.x;
  if (t >= N_NODES * 4) return;
  int n = t >> 2, h = t & 3;
  float sg = 1.f / (1.f + __expf(-sigma[0]));
  float o = el[n * 4 + h];
  int beg = col_ptr[n], end = col_ptr[n + 1];
  float s = 0.f;
  for (int p = beg; p < end; ++p) {
    int u = row[p];
    s += __expf(lrelu(er[u * 4 + h] + o));
  }
  cs[t] = (1.f - sg) * __logf(s) + 0.5f * __logf((float)max(end - beg, 1));
}

// ---- per-(dst,head): S_d inline, then w = exp(e - sg*lnS_d - cs[src]) -------
__global__ __launch_bounds__(256) void csr_weights(
    const int* __restrict__ row_ptr, const int* __restrict__ col,
    const float* __restrict__ el, const float* __restrict__ er,
    const float* __restrict__ cs, const float* __restrict__ sigma,
    float* __restrict__ w) {
  int t = blockIdx.x * blockDim.x + threadIdx.x;
  if (t >= N_NODES * 4) return;
  int d = t >> 2, h = t & 3;
  float sg = 1.f / (1.f + __expf(-sigma[0]));
  float er_d = er[d * 4 + h];
  int beg = row_ptr[d], end = row_ptr[d + 1];
  float S = 0.f;
  for (int p = beg; p < end; ++p) {
    int s_ = col[p];
    S += __expf(lrelu(el[s_ * 4 + h] + er_d));
  }
  float cdv = sg * __logf(S);
  for (int p = beg; p < end; ++p) {
    int s_ = col[p];
    float e = lrelu(el[s_ * 4 + h] + er_d);
    w[(size_t)p * 4 + h] = __expf(e - cdv - cs[s_ * 4 + h]);
  }
}

// -------- one hop: wave per dst node, bf16 in / bf16 out ---------------------
__global__ __launch_bounds__(256) void hop_kernel(
    const unsigned short* __restrict__ xin, unsigned short* __restrict__ xout,
    const int* __restrict__ row_ptr, const int* __restrict__ col,
    const float* __restrict__ w, const float* __restrict__ norm_in) {
  int wave = (int)(((size_t)blockIdx.x * blockDim.x + threadIdx.x) >> 6);
  int lane = threadIdx.x & 63;
  if (wave >= N_NODES) return;
  int d = wave;
  int hh = lane >> 4;                       // head owning this lane's 4 elems
  int beg = row_ptr[d], end = row_ptr[d + 1];
  float a0 = 0.f, a1 = 0.f, a2 = 0.f, a3 = 0.f;
  for (int p = beg; p < end; ++p) {
    int s = col[p];
    float wt = w[(size_t)p * 4 + hh];
    ushort4 u = *(const ushort4*)&xin[(size_t)s * HF + lane * 4];
    a0 = fmaf(wt, bf2f(u.x), a0);
    a1 = fmaf(wt, bf2f(u.y), a1);
    a2 = fmaf(wt, bf2f(u.z), a2);
    a3 = fmaf(wt, bf2f(u.w), a3);
  }
  float ni = norm_in[d];
  ushort4 o;
  o.x = f2bf(a0 * ni); o.y = f2bf(a1 * ni);
  o.z = f2bf(a2 * ni); o.w = f2bf(a3 * ni);
  *(ushort4*)&xout[(size_t)d * HF + lane * 4] = o;
}

// -------- hop-attention softmax over {h, x1, x2, x3} + combine ---------------
__global__ __launch_bounds__(256) void final_combine(
    const float* __restrict__ h0, const unsigned short* __restrict__ x1,
    const unsigned short* __restrict__ x2, const unsigned short* __restrict__ x3,
    const float* __restrict__ al, const float* __restrict__ hop_attn_r,
    float* __restrict__ out) {
  int n = blockIdx.x, t = threadIdx.x;
  size_t idx = (size_t)n * HF + t;
  float v0 = h0[idx], v1 = bf2f(x1[idx]), v2 = bf2f(x2[idx]), v3 = bf2f(x3[idx]);
  float wr = hop_attn_r[t];
  float b0 = v0 * wr, b1 = v1 * wr, b2 = v2 * wr, b3 = v3 * wr;
#pragma unroll
  for (int off = 32; off; off >>= 1) {
    b0 += __shfl_xor(b0, off);
    b1 += __shfl_xor(b1, off);
    b2 += __shfl_xor(b2, off);
    b3 += __shfl_xor(b3, off);
  }
  float a0 = al[n * 4 + (t >> 6)];
  b0 = lrelu(b0 + a0); b1 = lrelu(b1 + a0); b2 = lrelu(b2 + a0); b3 = lrelu(b3 + a0);
  float m = fmaxf(fmaxf(b0, b1), fmaxf(b2, b3));
  float e0 = expf(b0 - m), e1 = expf(b1 - m), e2 = expf(b2 - m), e3 = expf(b3 - m);
  float inv = 1.f / (e0 + e1 + e2 + e3);
  out[idx] = (v0 * e0 + v1 * e1 + v2 * e2 + v3 * e3) * inv;
}

extern "C" void kernel_launch(void* const* d_in, const int* in_sizes, int n_in,
                              void* d_out, int out_size, void* d_ws, size_t ws_size,
                              hipStream_t stream) {
  const float* feat       = (const float*)d_in[0];
  const int*   src        = (const int*)d_in[1];
  const int*   dst        = (const int*)d_in[2];
  const float* W          = (const float*)d_in[3];
  const float* attn_l     = (const float*)d_in[4];
  const float* attn_r     = (const float*)d_in[5];
  const float* hop_attn_l = (const float*)d_in[6];
  const float* hop_attn_r = (const float*)d_in[7];
  const float* sigma      = (const float*)d_in[8];
  float* out = (float*)d_out;

  char* ws = (char*)d_ws;
  size_t off = 0;
  auto alloc = [&](size_t bytes) -> void* {
    void* p = ws + off;
    off = align256(off + bytes);
    return p;
  };
  float*          hbuf  = (float*)alloc((size_t)N_NODES * HF * 4);          // h, f32
  unsigned short* h_bf  = (unsigned short*)alloc((size_t)N_NODES * HF * 2); // h, bf16
  unsigned short* x1    = (unsigned short*)alloc((size_t)N_NODES * HF * 2); // hop1 bf16
  unsigned short* x2    = (unsigned short*)alloc((size_t)N_NODES * HF * 2); // hop2 bf16
  unsigned short* x3    = (unsigned short*)alloc((size_t)N_NODES * HF * 2); // hop3 bf16
  float* w_csr  = (float*)alloc((size_t)N_EDGES * 4 * 4);    // CSR edge weights [pos][h]
  int*   col    = (int*)alloc((size_t)N_EDGES * 4);          // CSR payload: src
  int*   row    = (int*)alloc((size_t)N_EDGES * 4);          // CSC payload: dst
  int*   row_ptr= (int*)alloc((size_t)(N_NODES + 1) * 4);
  int*   col_ptr= (int*)alloc((size_t)(N_NODES + 1) * 4);
  float* el     = (float*)alloc((size_t)N_NODES * 4 * 4);
  float* er     = (float*)alloc((size_t)N_NODES * 4 * 4);
  float* al     = (float*)alloc((size_t)N_NODES * 4 * 4);
  float* cs     = (float*)alloc((size_t)N_NODES * 4 * 4);
  float* norm_in= (float*)alloc((size_t)N_NODES * 4);
  unsigned short* W_swz = (unsigned short*)alloc((size_t)65536 * 2); // bf16 frag-order W
  int* baseA    = (int*)alloc((size_t)(NBINS + 1) * 4);
  int* baseB    = (int*)alloc((size_t)(NBINS + 1) * 4);
  int* allocA   = (int*)alloc((size_t)NBINS * 4);
  int* allocB   = (int*)alloc((size_t)NBINS * 4);
  size_t zoff = off;
  int* binA     = (int*)alloc((size_t)NBINS * 4);
  int* binB     = (int*)alloc((size_t)NBINS * 4);
  size_t zbytes = off - zoff;
  // edge-record staging aliases bf16 hop buffers (dead before hops run)
  int2* recA = (int2*)x1;   // 6.4MB <= 25.6MB region
  int2* recB = (int2*)x2;

  hipMemsetAsync(ws + zoff, 0, zbytes, stream);

  // h = feat @ W via bf16 MFMA, with fused el/er/al dots + bf16 h copy
  w_swizzle<<<256, 256, 0, stream>>>(W, W_swz);
  mfma_gemm<<<(N_NODES + 63) / 64, 256, 0, stream>>>(
      feat, W_swz, hbuf, h_bf, attn_l, attn_r, hop_attn_l, el, er, al);
  // CSR/CSC build via two-level counting sort (no random scatter to HBM)
  const int EB = N_EDGES / 256;  // exactly 3125
  bin_hist<<<EB, 256, 0, stream>>>(src, dst, binA, binB);
  bin_scan<<<1, 64, 0, stream>>>(binA, binB, baseA, baseB, allocA, allocB, row_ptr, col_ptr);
  bin_scatter<<<EB, 256, 0, stream>>>(src, dst, allocA, allocB, recA, recB);
  bin_sort<<<dim3(NBINS, 2), 256, 0, stream>>>(recA, baseA, row_ptr, col,
                                               recB, baseB, col_ptr, row);
  norm_in_kernel<<<(N_NODES + 255) / 256, 256, 0, stream>>>(row_ptr, norm_in);
  // softmax log-coefficients + per-edge weights (node-centric, no atomics)
  const int NT = (N_NODES * 4 + 255) / 256;
  src_coef<<<NT, 256, 0, stream>>>(col_ptr, row, el, er, sigma, cs);
  csr_weights<<<NT, 256, 0, stream>>>(row_ptr, col, el, er, cs, sigma, w_csr);
  // K = 3 hops (bf16 gathers)
  const int HB = (N_NODES * 64 + 255) / 256;
  hop_kernel<<<HB, 256, 0, stream>>>(h_bf, x1, row_ptr, col, w_csr, norm_in);
  hop_kernel<<<HB, 256, 0, stream>>>(x1, x2, row_ptr, col, w_csr, norm_in);
  hop_kernel<<<HB, 256, 0, stream>>>(x2, x3, row_ptr, col, w_csr, norm_in);
  // hop-attention combine (f32 h + bf16 hops)
  final_combine<<<N_NODES, 256, 0, stream>>>(hbuf, x1, x2, x3, al, hop_attn_r, out);
}

// Round 6
// 604.075 us; speedup vs baseline: 2.3049x; 1.1828x over previous
//
#include <hip/hip_runtime.h>
#include <hip/hip_bf16.h>

#define N_NODES 50000
#define N_EDGES 800000
#define HF      256   // H_HEADS * F_OUT
#define SLOPE   0.2f
#define BIN_W   1024
#define NBINS   49    // ceil(N_NODES / BIN_W)

static inline size_t align256(size_t x) { return (x + 255) & ~(size_t)255; }

__device__ __forceinline__ float lrelu(float x) { return x > 0.f ? x : SLOPE * x; }

// exact bf16 -> f32 widening
__device__ __forceinline__ float bf2f(unsigned short b) {
  return __uint_as_float(((unsigned)b) << 16);
}
// f32 -> bf16 with round-to-nearest-even
__device__ __forceinline__ unsigned short f2bf(float f) {
  unsigned u = __float_as_uint(f);
  unsigned r = (u + 0x7FFFu + ((u >> 16) & 1u)) >> 16;
  return (unsigned short)r;
}

using f32x4 = __attribute__((ext_vector_type(4))) float;
using s16x8 = __attribute__((ext_vector_type(8))) short;  // 8 bf16 (4 VGPRs)

// ---- W pre-swizzle: f32 W[k][col] -> bf16 fragments [chunk][tile][lane][j] --
__global__ __launch_bounds__(256) void w_swizzle(
    const float* __restrict__ W, unsigned short* __restrict__ W_swz) {
  int t = blockIdx.x * 256 + threadIdx.x;   // 0..65535
  int k = t >> 8, col = t & 255;
  int kin = k & 31, chunk = k >> 5;
  int tile = col >> 4;
  int lane = ((kin >> 3) << 4) | (col & 15);
  int j = kin & 7;
  W_swz[(((chunk * 16 + tile) * 64 + lane) << 3) + j] = f2bf(W[t]);
}

// ---- MFMA GEMM h = feat @ W (bf16) + fused el/er/al dots; h stored bf16 -----
__global__ __launch_bounds__(256) void mfma_gemm(
    const float* __restrict__ feat, const unsigned short* __restrict__ W_swz,
    unsigned short* __restrict__ h_bf,
    const float* __restrict__ attn_l, const float* __restrict__ attn_r,
    const float* __restrict__ hop_attn_l,
    float* __restrict__ el, float* __restrict__ er, float* __restrict__ al) {
  __shared__ unsigned short sW[32768];      // 64KB: one K-half of fragments
  int tid = threadIdx.x;
  int w = tid >> 6, lane = tid & 63;
  int c15 = lane & 15, g = lane >> 4;
  int wave_row = blockIdx.x * 64 + w * 16;
  int row_a = wave_row + c15;
  bool va = row_a < N_NODES;

  float4 av[16];
  const float* ap = feat + (size_t)row_a * 256 + g * 8;
#pragma unroll
  for (int c = 0; c < 8; ++c) {
    if (va) {
      av[2 * c]     = *(const float4*)(ap + c * 32);
      av[2 * c + 1] = *(const float4*)(ap + c * 32 + 4);
    } else {
      av[2 * c] = make_float4(0.f, 0.f, 0.f, 0.f);
      av[2 * c + 1] = av[2 * c];
    }
  }

  f32x4 acc[16];
#pragma unroll
  for (int t = 0; t < 16; ++t) acc[t] = (f32x4){0.f, 0.f, 0.f, 0.f};

  const s16x8* sWf = (const s16x8*)sW;
#pragma unroll
  for (int hf = 0; hf < 2; ++hf) {
    if (hf) __syncthreads();
    {
      const uint4* gw = (const uint4*)(W_swz + hf * 32768);
      uint4* sw4 = (uint4*)sW;
      for (int i = tid; i < 4096; i += 256) sw4[i] = gw[i];
    }
    __syncthreads();
#pragma unroll
    for (int cc = 0; cc < 4; ++cc) {
      int c = hf * 4 + cc;
      s16x8 a;
      const float* p0 = (const float*)&av[2 * c];
#pragma unroll
      for (int j = 0; j < 8; ++j) a[j] = (short)f2bf(p0[j]);
#pragma unroll
      for (int t = 0; t < 16; ++t) {
        s16x8 b = sWf[(cc * 16 + t) * 64 + lane];
        acc[t] = __builtin_amdgcn_mfma_f32_16x16x32_bf16(a, b, acc[t], 0, 0, 0);
      }
    }
  }

  // fused epilogue: dots
  float pl[16], pr[16], pa[16];
#pragma unroll
  for (int i = 0; i < 16; ++i) { pl[i] = 0.f; pr[i] = 0.f; pa[i] = 0.f; }
#pragma unroll
  for (int t = 0; t < 16; ++t) {
    int colv = t * 16 + c15;
    float la = attn_l[colv], ra = attn_r[colv], ha = hop_attn_l[colv];
    int h = t >> 2;
#pragma unroll
    for (int r = 0; r < 4; ++r) {
      pl[r * 4 + h] = fmaf(acc[t][r], la, pl[r * 4 + h]);
      pr[r * 4 + h] = fmaf(acc[t][r], ra, pr[r * 4 + h]);
      pa[r * 4 + h] = fmaf(acc[t][r], ha, pa[r * 4 + h]);
    }
  }
#pragma unroll
  for (int i = 0; i < 16; ++i) {
#pragma unroll
    for (int off = 8; off; off >>= 1) {
      pl[i] += __shfl_xor(pl[i], off);
      pr[i] += __shfl_xor(pr[i], off);
      pa[i] += __shfl_xor(pa[i], off);
    }
  }
  int rowg = wave_row + g * 4;
  if (c15 == 0) {
#pragma unroll
    for (int r = 0; r < 4; ++r) {
      if (rowg + r < N_NODES) {
        *(float4*)&el[(rowg + r) * 4] = make_float4(pl[r*4+0], pl[r*4+1], pl[r*4+2], pl[r*4+3]);
        *(float4*)&er[(rowg + r) * 4] = make_float4(pr[r*4+0], pr[r*4+1], pr[r*4+2], pr[r*4+3]);
        *(float4*)&al[(rowg + r) * 4] = make_float4(pa[r*4+0], pa[r*4+1], pa[r*4+2], pa[r*4+3]);
      }
    }
  }
#pragma unroll
  for (int r = 0; r < 4; ++r) {
    int row = rowg + r;
    if (row < N_NODES) {
#pragma unroll
      for (int t = 0; t < 16; ++t) {
        h_bf[(size_t)row * HF + t * 16 + c15] = f2bf(acc[t][r]);
      }
    }
  }
}

// -------- pass A: per-bin edge histograms (LDS-aggregated) -------------------
__global__ __launch_bounds__(256) void bin_hist(
    const int* __restrict__ src, const int* __restrict__ dst,
    int* __restrict__ binA, int* __restrict__ binB) {
  __shared__ int cA[NBINS], cB[NBINS];
  int t = threadIdx.x;
  if (t < NBINS) { cA[t] = 0; cB[t] = 0; }
  __syncthreads();
  int e = blockIdx.x * 256 + t;
  int s = src[e], d = dst[e];
  atomicAdd(&cA[d >> 10], 1);
  atomicAdd(&cB[s >> 10], 1);
  __syncthreads();
  if (t < NBINS) {
    if (cA[t]) atomicAdd(&binA[t], cA[t]);
    if (cB[t]) atomicAdd(&binB[t], cB[t]);
  }
}

// -------- pass B: scan bin counts -> bases + alloc cursors -------------------
__global__ void bin_scan(const int* __restrict__ binA, const int* __restrict__ binB,
                         int* __restrict__ baseA, int* __restrict__ baseB,
                         int* __restrict__ allocA, int* __restrict__ allocB,
                         int* __restrict__ row_ptr, int* __restrict__ col_ptr) {
  int t = threadIdx.x;  // 64 threads, one wave
  int vA = (t < NBINS) ? binA[t] : 0;
  int vB = (t < NBINS) ? binB[t] : 0;
  int xA = vA, xB = vB;
#pragma unroll
  for (int off = 1; off < 64; off <<= 1) {
    int yA = __shfl_up(xA, off);
    int yB = __shfl_up(xB, off);
    if (t >= off) { xA += yA; xB += yB; }
  }
  if (t < NBINS) {
    baseA[t] = xA - vA; allocA[t] = xA - vA;
    baseB[t] = xB - vB; allocB[t] = xB - vB;
  }
  if (t == NBINS - 1) {
    baseA[NBINS] = xA; baseB[NBINS] = xB;
    row_ptr[N_NODES] = N_EDGES; col_ptr[N_NODES] = N_EDGES;
  }
}

// -------- pass C: chunked binning of 8B edge records -------------------------
__global__ __launch_bounds__(256) void bin_scatter(
    const int* __restrict__ src, const int* __restrict__ dst,
    int* __restrict__ allocA, int* __restrict__ allocB,
    int2* __restrict__ recA, int2* __restrict__ recB) {
  __shared__ int cA[NBINS], cB[NBINS], bA[NBINS], bB[NBINS];
  int t = threadIdx.x;
  if (t < NBINS) { cA[t] = 0; cB[t] = 0; }
  __syncthreads();
  int e = blockIdx.x * 256 + t;
  int s = src[e], d = dst[e];
  int ba = d >> 10, bb = s >> 10;
  int ra = atomicAdd(&cA[ba], 1);
  int rb = atomicAdd(&cB[bb], 1);
  __syncthreads();
  if (t < NBINS) {
    bA[t] = cA[t] ? atomicAdd(&allocA[t], cA[t]) : 0;
    bB[t] = cB[t] ? atomicAdd(&allocB[t], cB[t]) : 0;
  }
  __syncthreads();
  recA[bA[ba] + ra] = make_int2(s, d);  // payload=src, key=dst
  recB[bB[bb] + rb] = make_int2(d, s);  // payload=dst, key=src
}

// -------- pass D: in-LDS counting sort per bin -> ptr + payload arrays -------
__global__ __launch_bounds__(256) void bin_sort(
    const int2* __restrict__ recA, const int* __restrict__ baseA,
    int* __restrict__ row_ptr, int* __restrict__ outA,
    const int2* __restrict__ recB, const int* __restrict__ baseB,
    int* __restrict__ col_ptr, int* __restrict__ outB) {
  const int2* rec; const int* base; int* ptr; int* out;
  if (blockIdx.y == 0) { rec = recA; base = baseA; ptr = row_ptr; out = outA; }
  else                 { rec = recB; base = baseB; ptr = col_ptr; out = outB; }
  __shared__ int hist[BIN_W];
  __shared__ int wsum[4];
  int b = blockIdx.x, t = threadIdx.x;
  int n0 = b << 10;
  int nn = min(BIN_W, N_NODES - n0);
  int beg = base[b], end = base[b + 1];
  for (int i = t; i < BIN_W; i += 256) hist[i] = 0;
  __syncthreads();
  for (int p = beg + t; p < end; p += 256)
    atomicAdd(&hist[rec[p].y - n0], 1);
  __syncthreads();
  int i0 = t * 4;
  int h0 = hist[i0], h1 = hist[i0 + 1], h2 = hist[i0 + 2], h3 = hist[i0 + 3];
  int sum4 = h0 + h1 + h2 + h3;
  int x = sum4;
  int lane = t & 63, wid = t >> 6;
#pragma unroll
  for (int off = 1; off < 64; off <<= 1) {
    int y = __shfl_up(x, off);
    if (lane >= off) x += y;
  }
  if (lane == 63) wsum[wid] = x;
  __syncthreads();
  int wpre = 0;
#pragma unroll
  for (int wj = 0; wj < 4; ++wj) wpre += (wj < wid) ? wsum[wj] : 0;
  int excl = wpre + x - sum4;
  int e0 = excl, e1 = excl + h0, e2 = excl + h0 + h1, e3 = excl + h0 + h1 + h2;
  hist[i0] = e0; hist[i0 + 1] = e1; hist[i0 + 2] = e2; hist[i0 + 3] = e3;
  if (i0 + 0 < nn) ptr[n0 + i0 + 0] = beg + e0;
  if (i0 + 1 < nn) ptr[n0 + i0 + 1] = beg + e1;
  if (i0 + 2 < nn) ptr[n0 + i0 + 2] = beg + e2;
  if (i0 + 3 < nn) ptr[n0 + i0 + 3] = beg + e3;
  __syncthreads();
  for (int p = beg + t; p < end; p += 256) {
    int2 r = rec[p];
    int pos = atomicAdd(&hist[r.y - n0], 1);
    out[beg + pos] = r.x;
  }
}

// ---------------- norm_in from row_ptr diffs ---------------------------------
__global__ void norm_in_kernel(const int* __restrict__ row_ptr, float* __restrict__ norm_in) {
  int n = blockIdx.x * blockDim.x + threadIdx.x;
  if (n >= N_NODES) return;
  int deg = row_ptr[n + 1] - row_ptr[n];
  norm_in[n] = sqrtf((float)max(deg, 1));
}

// ---- per-src-node: cs = (1-sg)*ln(S_src) + 0.5*ln(outdeg); wave per node ----
__global__ __launch_bounds__(256) void src_coef(
    const int* __restrict__ col_ptr, const int* __restrict__ row,
    const float4* __restrict__ el4, const float4* __restrict__ er4,
    const float* __restrict__ sigma, float4* __restrict__ cs4) {
  int n = (int)(((size_t)blockIdx.x * blockDim.x + threadIdx.x) >> 6);
  int lane = threadIdx.x & 63;
  if (n >= N_NODES) return;
  int beg = col_ptr[n], end = col_ptr[n + 1];
  float4 o = el4[n];
  float s0 = 0.f, s1 = 0.f, s2 = 0.f, s3 = 0.f;
  for (int p = beg + lane; p < end; p += 64) {
    int u = row[p];
    float4 e = er4[u];
    s0 += __expf(lrelu(e.x + o.x));
    s1 += __expf(lrelu(e.y + o.y));
    s2 += __expf(lrelu(e.z + o.z));
    s3 += __expf(lrelu(e.w + o.w));
  }
#pragma unroll
  for (int off = 32; off; off >>= 1) {
    s0 += __shfl_xor(s0, off); s1 += __shfl_xor(s1, off);
    s2 += __shfl_xor(s2, off); s3 += __shfl_xor(s3, off);
  }
  if (lane == 0) {
    float sg = 1.f / (1.f + __expf(-sigma[0]));
    float c = 0.5f * __logf((float)max(end - beg, 1));
    float k = 1.f - sg;
    cs4[n] = make_float4(k * __logf(s0) + c, k * __logf(s1) + c,
                         k * __logf(s2) + c, k * __logf(s3) + c);
  }
}

// ---- per-dst-node: S_d inline, then w4 = exp(e - sg*lnS_d - cs[src]) --------
__global__ __launch_bounds__(256) void csr_weights(
    const int* __restrict__ row_ptr, const int* __restrict__ col,
    const float4* __restrict__ el4, const float4* __restrict__ er4,
    const float4* __restrict__ cs4, const float* __restrict__ sigma,
    float4* __restrict__ w4) {
  int d = (int)(((size_t)blockIdx.x * blockDim.x + threadIdx.x) >> 6);
  int lane = threadIdx.x & 63;
  if (d >= N_NODES) return;
  int beg = row_ptr[d], end = row_ptr[d + 1];
  if (beg == end) return;
  float4 o = er4[d];
  float s0 = 0.f, s1 = 0.f, s2 = 0.f, s3 = 0.f;
  for (int p = beg + lane; p < end; p += 64) {
    int s_ = col[p];
    float4 e = el4[s_];
    s0 += __expf(lrelu(e.x + o.x));
    s1 += __expf(lrelu(e.y + o.y));
    s2 += __expf(lrelu(e.z + o.z));
    s3 += __expf(lrelu(e.w + o.w));
  }
#pragma unroll
  for (int off = 32; off; off >>= 1) {
    s0 += __shfl_xor(s0, off); s1 += __shfl_xor(s1, off);
    s2 += __shfl_xor(s2, off); s3 += __shfl_xor(s3, off);
  }
  float sg = 1.f / (1.f + __expf(-sigma[0]));
  float c0 = sg * __logf(s0), c1 = sg * __logf(s1);
  float c2 = sg * __logf(s2), c3 = sg * __logf(s3);
  for (int p = beg + lane; p < end; p += 64) {
    int s_ = col[p];
    float4 e = el4[s_];
    float4 cc = cs4[s_];
    float4 wv;
    wv.x = __expf(lrelu(e.x + o.x) - c0 - cc.x);
    wv.y = __expf(lrelu(e.y + o.y) - c1 - cc.y);
    wv.z = __expf(lrelu(e.z + o.z) - c2 - cc.z);
    wv.w = __expf(lrelu(e.w + o.w) - c3 - cc.w);
    w4[p] = wv;
  }
}

// -------- one hop: wave per dst node, unroll-4 edge loop (MLP) ---------------
__global__ __launch_bounds__(256) void hop_kernel(
    const unsigned short* __restrict__ xin, unsigned short* __restrict__ xout,
    const int* __restrict__ row_ptr, const int* __restrict__ col,
    const float* __restrict__ w, const float* __restrict__ norm_in) {
  int d = (int)(((size_t)blockIdx.x * blockDim.x + threadIdx.x) >> 6);
  int lane = threadIdx.x & 63;
  if (d >= N_NODES) return;
  int hh = lane >> 4;
  int beg = row_ptr[d], end = row_ptr[d + 1];
  float a0 = 0.f, a1 = 0.f, a2 = 0.f, a3 = 0.f;
  const unsigned short* xl = xin + lane * 4;
  int p = beg;
  for (; p + 3 < end; p += 4) {
    int s0 = col[p], s1 = col[p + 1], s2 = col[p + 2], s3 = col[p + 3];
    float w0 = w[(size_t)p * 4 + hh];
    float w1 = w[(size_t)p * 4 + 4 + hh];
    float w2 = w[(size_t)p * 4 + 8 + hh];
    float w3 = w[(size_t)p * 4 + 12 + hh];
    ushort4 u0 = *(const ushort4*)(xl + (size_t)s0 * HF);
    ushort4 u1 = *(const ushort4*)(xl + (size_t)s1 * HF);
    ushort4 u2 = *(const ushort4*)(xl + (size_t)s2 * HF);
    ushort4 u3 = *(const ushort4*)(xl + (size_t)s3 * HF);
    a0 = fmaf(w0, bf2f(u0.x), a0); a1 = fmaf(w0, bf2f(u0.y), a1);
    a2 = fmaf(w0, bf2f(u0.z), a2); a3 = fmaf(w0, bf2f(u0.w), a3);
    a0 = fmaf(w1, bf2f(u1.x), a0); a1 = fmaf(w1, bf2f(u1.y), a1);
    a2 = fmaf(w1, bf2f(u1.z), a2); a3 = fmaf(w1, bf2f(u1.w), a3);
    a0 = fmaf(w2, bf2f(u2.x), a0); a1 = fmaf(w2, bf2f(u2.y), a1);
    a2 = fmaf(w2, bf2f(u2.z), a2); a3 = fmaf(w2, bf2f(u2.w), a3);
    a0 = fmaf(w3, bf2f(u3.x), a0); a1 = fmaf(w3, bf2f(u3.y), a1);
    a2 = fmaf(w3, bf2f(u3.z), a2); a3 = fmaf(w3, bf2f(u3.w), a3);
  }
  for (; p < end; ++p) {
    int s = col[p];
    float wt = w[(size_t)p * 4 + hh];
    ushort4 u = *(const ushort4*)(xl + (size_t)s * HF);
    a0 = fmaf(wt, bf2f(u.x), a0); a1 = fmaf(wt, bf2f(u.y), a1);
    a2 = fmaf(wt, bf2f(u.z), a2); a3 = fmaf(wt, bf2f(u.w), a3);
  }
  float ni = norm_in[d];
  ushort4 o;
  o.x = f2bf(a0 * ni); o.y = f2bf(a1 * ni);
  o.z = f2bf(a2 * ni); o.w = f2bf(a3 * ni);
  *(ushort4*)&xout[(size_t)d * HF + lane * 4] = o;
}

// -------- hop-attention softmax over {h, x1, x2, x3} + combine ---------------
__global__ __launch_bounds__(256) void final_combine(
    const unsigned short* __restrict__ h0, const unsigned short* __restrict__ x1,
    const unsigned short* __restrict__ x2, const unsigned short* __restrict__ x3,
    const float* __restrict__ al, const float* __restrict__ hop_attn_r,
    float* __restrict__ out) {
  int n = blockIdx.x, t = threadIdx.x;
  size_t idx = (size_t)n * HF + t;
  float v0 = bf2f(h0[idx]), v1 = bf2f(x1[idx]), v2 = bf2f(x2[idx]), v3 = bf2f(x3[idx]);
  float wr = hop_attn_r[t];
  float b0 = v0 * wr, b1 = v1 * wr, b2 = v2 * wr, b3 = v3 * wr;
#pragma unroll
  for (int off = 32; off; off >>= 1) {
    b0 += __shfl_xor(b0, off);
    b1 += __shfl_xor(b1, off);
    b2 += __shfl_xor(b2, off);
    b3 += __shfl_xor(b3, off);
  }
  float a0 = al[n * 4 + (t >> 6)];
  b0 = lrelu(b0 + a0); b1 = lrelu(b1 + a0); b2 = lrelu(b2 + a0); b3 = lrelu(b3 + a0);
  float m = fmaxf(fmaxf(b0, b1), fmaxf(b2, b3));
  float e0 = expf(b0 - m), e1 = expf(b1 - m), e2 = expf(b2 - m), e3 = expf(b3 - m);
  float inv = 1.f / (e0 + e1 + e2 + e3);
  out[idx] = (v0 * e0 + v1 * e1 + v2 * e2 + v3 * e3) * inv;
}

extern "C" void kernel_launch(void* const* d_in, const int* in_sizes, int n_in,
                              void* d_out, int out_size, void* d_ws, size_t ws_size,
                              hipStream_t stream) {
  const float* feat       = (const float*)d_in[0];
  const int*   src        = (const int*)d_in[1];
  const int*   dst        = (const int*)d_in[2];
  const float* W          = (const float*)d_in[3];
  const float* attn_l     = (const float*)d_in[4];
  const float* attn_r     = (const float*)d_in[5];
  const float* hop_attn_l = (const float*)d_in[6];
  const float* hop_attn_r = (const float*)d_in[7];
  const float* sigma      = (const float*)d_in[8];
  float* out = (float*)d_out;

  char* ws = (char*)d_ws;
  size_t off = 0;
  auto alloc = [&](size_t bytes) -> void* {
    void* p = ws + off;
    off = align256(off + bytes);
    return p;
  };
  unsigned short* h_bf  = (unsigned short*)alloc((size_t)N_NODES * HF * 2); // h, bf16
  unsigned short* x1    = (unsigned short*)alloc((size_t)N_NODES * HF * 2);
  unsigned short* x2    = (unsigned short*)alloc((size_t)N_NODES * HF * 2);
  unsigned short* x3    = (unsigned short*)alloc((size_t)N_NODES * HF * 2);
  float* w_csr  = (float*)alloc((size_t)N_EDGES * 4 * 4);
  int*   col    = (int*)alloc((size_t)N_EDGES * 4);          // CSR payload: src
  int*   row    = (int*)alloc((size_t)N_EDGES * 4);          // CSC payload: dst
  int*   row_ptr= (int*)alloc((size_t)(N_NODES + 1) * 4);
  int*   col_ptr= (int*)alloc((size_t)(N_NODES + 1) * 4);
  float* el     = (float*)alloc((size_t)N_NODES * 4 * 4);
  float* er     = (float*)alloc((size_t)N_NODES * 4 * 4);
  float* al     = (float*)alloc((size_t)N_NODES * 4 * 4);
  float* cs     = (float*)alloc((size_t)N_NODES * 4 * 4);
  float* norm_in= (float*)alloc((size_t)N_NODES * 4);
  unsigned short* W_swz = (unsigned short*)alloc((size_t)65536 * 2);
  int* baseA    = (int*)alloc((size_t)(NBINS + 1) * 4);
  int* baseB    = (int*)alloc((size_t)(NBINS + 1) * 4);
  int* allocA   = (int*)alloc((size_t)NBINS * 4);
  int* allocB   = (int*)alloc((size_t)NBINS * 4);
  size_t zoff = off;
  int* binA     = (int*)alloc((size_t)NBINS * 4);
  int* binB     = (int*)alloc((size_t)NBINS * 4);
  size_t zbytes = off - zoff;
  // edge-record staging aliases bf16 hop buffers (dead before hops run)
  int2* recA = (int2*)x1;
  int2* recB = (int2*)x2;

  hipMemsetAsync(ws + zoff, 0, zbytes, stream);

  // h = feat @ W via bf16 MFMA, fused el/er/al dots, bf16 h out
  w_swizzle<<<256, 256, 0, stream>>>(W, W_swz);
  mfma_gemm<<<(N_NODES + 63) / 64, 256, 0, stream>>>(
      feat, W_swz, h_bf, attn_l, attn_r, hop_attn_l, el, er, al);
  // CSR/CSC build via two-level counting sort
  const int EB = N_EDGES / 256;  // exactly 3125
  bin_hist<<<EB, 256, 0, stream>>>(src, dst, binA, binB);
  bin_scan<<<1, 64, 0, stream>>>(binA, binB, baseA, baseB, allocA, allocB, row_ptr, col_ptr);
  bin_scatter<<<EB, 256, 0, stream>>>(src, dst, allocA, allocB, recA, recB);
  bin_sort<<<dim3(NBINS, 2), 256, 0, stream>>>(recA, baseA, row_ptr, col,
                                               recB, baseB, col_ptr, row);
  norm_in_kernel<<<(N_NODES + 255) / 256, 256, 0, stream>>>(row_ptr, norm_in);
  // softmax coefficients + per-edge weights (wave per node, lane per edge)
  const int HB = (N_NODES * 64 + 255) / 256;  // 12500 blocks
  src_coef<<<HB, 256, 0, stream>>>(col_ptr, row, (const float4*)el, (const float4*)er,
                                   sigma, (float4*)cs);
  csr_weights<<<HB, 256, 0, stream>>>(row_ptr, col, (const float4*)el, (const float4*)er,
                                      (const float4*)cs, sigma, (float4*)w_csr);
  // K = 3 hops (bf16 gathers, unroll-4)
  hop_kernel<<<HB, 256, 0, stream>>>(h_bf, x1, row_ptr, col, w_csr, norm_in);
  hop_kernel<<<HB, 256, 0, stream>>>(x1, x2, row_ptr, col, w_csr, norm_in);
  hop_kernel<<<HB, 256, 0, stream>>>(x2, x3, row_ptr, col, w_csr, norm_in);
  // hop-attention combine (all-bf16 hop stack)
  final_combine<<<N_NODES, 256, 0, stream>>>(h_bf, x1, x2, x3, al, hop_attn_r, out);
}

// Round 8
// 544.283 us; speedup vs baseline: 2.5581x; 1.1099x over previous
//
#include <hip/hip_runtime.h>
#include <hip/hip_bf16.h>

#define N_NODES 50000
#define N_EDGES 800000
#define HF      256   // H_HEADS * F_OUT
#define SLOPE   0.2f
#define BIN_W   1024
#define NBINS   49    // ceil(N_NODES / BIN_W)
#define G_SUB   32    // sub-cursors per bin (atomic de-contention)

static inline size_t align256(size_t x) { return (x + 255) & ~(size_t)255; }

__device__ __forceinline__ float lrelu(float x) { return x > 0.f ? x : SLOPE * x; }

// exact bf16 -> f32 widening
__device__ __forceinline__ float bf2f(unsigned short b) {
  return __uint_as_float(((unsigned)b) << 16);
}
// f32 -> bf16 with round-to-nearest-even
__device__ __forceinline__ unsigned short f2bf(float f) {
  unsigned u = __float_as_uint(f);
  unsigned r = (u + 0x7FFFu + ((u >> 16) & 1u)) >> 16;
  return (unsigned short)r;
}

using f32x4 = __attribute__((ext_vector_type(4))) float;
using s16x8 = __attribute__((ext_vector_type(8))) short;  // 8 bf16 (4 VGPRs)

// ---- W pre-swizzle: f32 W[k][col] -> bf16 fragments [chunk][tile][lane][j] --
__global__ __launch_bounds__(256) void w_swizzle(
    const float* __restrict__ W, unsigned short* __restrict__ W_swz) {
  int t = blockIdx.x * 256 + threadIdx.x;   // 0..65535
  int k = t >> 8, col = t & 255;
  int kin = k & 31, chunk = k >> 5;
  int tile = col >> 4;
  int lane = ((kin >> 3) << 4) | (col & 15);
  int j = kin & 7;
  W_swz[(((chunk * 16 + tile) * 64 + lane) << 3) + j] = f2bf(W[t]);
}

// ---- MFMA GEMM h = feat @ W (bf16) + fused el/er/al dots; h stored bf16 -----
__global__ __launch_bounds__(256) void mfma_gemm(
    const float* __restrict__ feat, const unsigned short* __restrict__ W_swz,
    unsigned short* __restrict__ h_bf,
    const float* __restrict__ attn_l, const float* __restrict__ attn_r,
    const float* __restrict__ hop_attn_l,
    float* __restrict__ el, float* __restrict__ er, float* __restrict__ al) {
  __shared__ unsigned short sW[32768];      // 64KB: one K-half of fragments
  int tid = threadIdx.x;
  int w = tid >> 6, lane = tid & 63;
  int c15 = lane & 15, g = lane >> 4;
  int wave_row = blockIdx.x * 64 + w * 16;
  int row_a = wave_row + c15;
  bool va = row_a < N_NODES;

  float4 av[16];
  const float* ap = feat + (size_t)row_a * 256 + g * 8;
#pragma unroll
  for (int c = 0; c < 8; ++c) {
    if (va) {
      av[2 * c]     = *(const float4*)(ap + c * 32);
      av[2 * c + 1] = *(const float4*)(ap + c * 32 + 4);
    } else {
      av[2 * c] = make_float4(0.f, 0.f, 0.f, 0.f);
      av[2 * c + 1] = av[2 * c];
    }
  }

  f32x4 acc[16];
#pragma unroll
  for (int t = 0; t < 16; ++t) acc[t] = (f32x4){0.f, 0.f, 0.f, 0.f};

  const s16x8* sWf = (const s16x8*)sW;
#pragma unroll
  for (int hf = 0; hf < 2; ++hf) {
    if (hf) __syncthreads();
    {
      const uint4* gw = (const uint4*)(W_swz + hf * 32768);
      uint4* sw4 = (uint4*)sW;
      for (int i = tid; i < 4096; i += 256) sw4[i] = gw[i];
    }
    __syncthreads();
#pragma unroll
    for (int cc = 0; cc < 4; ++cc) {
      int c = hf * 4 + cc;
      s16x8 a;
      const float* p0 = (const float*)&av[2 * c];
#pragma unroll
      for (int j = 0; j < 8; ++j) a[j] = (short)f2bf(p0[j]);
#pragma unroll
      for (int t = 0; t < 16; ++t) {
        s16x8 b = sWf[(cc * 16 + t) * 64 + lane];
        acc[t] = __builtin_amdgcn_mfma_f32_16x16x32_bf16(a, b, acc[t], 0, 0, 0);
      }
    }
  }

  // fused epilogue: dots
  float pl[16], pr[16], pa[16];
#pragma unroll
  for (int i = 0; i < 16; ++i) { pl[i] = 0.f; pr[i] = 0.f; pa[i] = 0.f; }
#pragma unroll
  for (int t = 0; t < 16; ++t) {
    int colv = t * 16 + c15;
    float la = attn_l[colv], ra = attn_r[colv], ha = hop_attn_l[colv];
    int h = t >> 2;
#pragma unroll
    for (int r = 0; r < 4; ++r) {
      pl[r * 4 + h] = fmaf(acc[t][r], la, pl[r * 4 + h]);
      pr[r * 4 + h] = fmaf(acc[t][r], ra, pr[r * 4 + h]);
      pa[r * 4 + h] = fmaf(acc[t][r], ha, pa[r * 4 + h]);
    }
  }
#pragma unroll
  for (int i = 0; i < 16; ++i) {
#pragma unroll
    for (int off = 8; off; off >>= 1) {
      pl[i] += __shfl_xor(pl[i], off);
      pr[i] += __shfl_xor(pr[i], off);
      pa[i] += __shfl_xor(pa[i], off);
    }
  }
  int rowg = wave_row + g * 4;
  if (c15 == 0) {
#pragma unroll
    for (int r = 0; r < 4; ++r) {
      if (rowg + r < N_NODES) {
        *(float4*)&el[(rowg + r) * 4] = make_float4(pl[r*4+0], pl[r*4+1], pl[r*4+2], pl[r*4+3]);
        *(float4*)&er[(rowg + r) * 4] = make_float4(pr[r*4+0], pr[r*4+1], pr[r*4+2], pr[r*4+3]);
        *(float4*)&al[(rowg + r) * 4] = make_float4(pa[r*4+0], pa[r*4+1], pa[r*4+2], pa[r*4+3]);
      }
    }
  }
#pragma unroll
  for (int r = 0; r < 4; ++r) {
    int row = rowg + r;
    if (row < N_NODES) {
#pragma unroll
      for (int t = 0; t < 16; ++t) {
        h_bf[(size_t)row * HF + t * 16 + c15] = f2bf(acc[t][r]);
      }
    }
  }
}

// -------- pass A: per-bin edge histograms -> per-(bin, g) counts -------------
__global__ __launch_bounds__(256) void bin_hist(
    const int* __restrict__ src, const int* __restrict__ dst,
    int* __restrict__ cntA, int* __restrict__ cntB) {
  __shared__ int cA[NBINS], cB[NBINS];
  int t = threadIdx.x;
  if (t < NBINS) { cA[t] = 0; cB[t] = 0; }
  __syncthreads();
  int e = blockIdx.x * 256 + t;
  int s = src[e], d = dst[e];
  atomicAdd(&cA[d >> 10], 1);
  atomicAdd(&cB[s >> 10], 1);
  __syncthreads();
  int g = blockIdx.x & (G_SUB - 1);
  if (t < NBINS) {
    if (cA[t]) atomicAdd(&cntA[t * G_SUB + g], cA[t]);
    if (cB[t]) atomicAdd(&cntB[t * G_SUB + g], cB[t]);
  }
}

// -------- pass B: scan (bin,g) counts -> cursors + per-bin bases -------------
__global__ __launch_bounds__(1024) void scan2(
    const int* __restrict__ cntA, int* __restrict__ curA, int* __restrict__ baseA,
    const int* __restrict__ cntB, int* __restrict__ curB, int* __restrict__ baseB,
    int* __restrict__ row_ptr, int* __restrict__ col_ptr) {
  const int* cnt = (blockIdx.x == 0) ? cntA : cntB;
  int* cur  = (blockIdx.x == 0) ? curA : curB;
  int* base = (blockIdx.x == 0) ? baseA : baseB;
  __shared__ int wsum[16];
  __shared__ int carry_s;
  if (threadIdx.x == 0) carry_s = 0;
  __syncthreads();
  const int NTOT = NBINS * G_SUB;  // 1568
  for (int b0 = 0; b0 < NTOT; b0 += 1024) {
    int i = b0 + threadIdx.x;
    int v = (i < NTOT) ? cnt[i] : 0;
    int lane = threadIdx.x & 63, wid = threadIdx.x >> 6;
    int x = v;
#pragma unroll
    for (int off = 1; off < 64; off <<= 1) {
      int y = __shfl_up(x, off, 64);
      if (lane >= off) x += y;
    }
    if (lane == 63) wsum[wid] = x;
    __syncthreads();
    if (threadIdx.x < 16) {
      int s = wsum[threadIdx.x];
#pragma unroll
      for (int off = 1; off < 16; off <<= 1) {
        int y = __shfl_up(s, off, 16);
        if ((int)(threadIdx.x & 15) >= off) s += y;
      }
      wsum[threadIdx.x] = s;
    }
    __syncthreads();
    int carry = carry_s;
    int pre = (wid > 0) ? wsum[wid - 1] : 0;
    int incl = x + pre + carry;
    int excl = incl - v;
    if (i < NTOT) {
      cur[i] = excl;
      if ((i & (G_SUB - 1)) == 0) base[i / G_SUB] = excl;
    }
    __syncthreads();
    if (threadIdx.x == 1023) carry_s = incl;
    __syncthreads();
  }
  if (threadIdx.x == 0) {
    base[NBINS] = N_EDGES;
    if (blockIdx.x == 0) row_ptr[N_NODES] = N_EDGES;
    else                 col_ptr[N_NODES] = N_EDGES;
  }
}

// -------- pass C: chunked binning of 8B edge records (de-contended) ----------
__global__ __launch_bounds__(256) void bin_scatter(
    const int* __restrict__ src, const int* __restrict__ dst,
    int* __restrict__ curA, int* __restrict__ curB,
    int2* __restrict__ recA, int2* __restrict__ recB) {
  __shared__ int cA[NBINS], cB[NBINS], bA[NBINS], bB[NBINS];
  int t = threadIdx.x;
  if (t < NBINS) { cA[t] = 0; cB[t] = 0; }
  __syncthreads();
  int e = blockIdx.x * 256 + t;
  int s = src[e], d = dst[e];
  int ba = d >> 10, bb = s >> 10;
  int ra = atomicAdd(&cA[ba], 1);
  int rb = atomicAdd(&cB[bb], 1);
  __syncthreads();
  int g = blockIdx.x & (G_SUB - 1);
  if (t < NBINS) {
    bA[t] = cA[t] ? atomicAdd(&curA[t * G_SUB + g], cA[t]) : 0;
    bB[t] = cB[t] ? atomicAdd(&curB[t * G_SUB + g], cB[t]) : 0;
  }
  __syncthreads();
  recA[bA[ba] + ra] = make_int2(s, d);  // payload=src, key=dst
  recB[bB[bb] + rb] = make_int2(d, s);  // payload=dst, key=src
}

// -------- pass D: in-LDS counting sort per bin -> ptr + payload arrays -------
__global__ __launch_bounds__(256) void bin_sort(
    const int2* __restrict__ recA, const int* __restrict__ baseA,
    int* __restrict__ row_ptr, int* __restrict__ outA,
    const int2* __restrict__ recB, const int* __restrict__ baseB,
    int* __restrict__ col_ptr, int* __restrict__ outB) {
  const int2* rec; const int* base; int* ptr; int* out;
  if (blockIdx.y == 0) { rec = recA; base = baseA; ptr = row_ptr; out = outA; }
  else                 { rec = recB; base = baseB; ptr = col_ptr; out = outB; }
  __shared__ int hist[BIN_W];
  __shared__ int wsum[4];
  int b = blockIdx.x, t = threadIdx.x;
  int n0 = b << 10;
  int nn = min(BIN_W, N_NODES - n0);
  int beg = base[b], end = base[b + 1];
  for (int i = t; i < BIN_W; i += 256) hist[i] = 0;
  __syncthreads();
  for (int p = beg + t; p < end; p += 256)
    atomicAdd(&hist[rec[p].y - n0], 1);
  __syncthreads();
  int i0 = t * 4;
  int h0 = hist[i0], h1 = hist[i0 + 1], h2 = hist[i0 + 2], h3 = hist[i0 + 3];
  int sum4 = h0 + h1 + h2 + h3;
  int x = sum4;
  int lane = t & 63, wid = t >> 6;
#pragma unroll
  for (int off = 1; off < 64; off <<= 1) {
    int y = __shfl_up(x, off);
    if (lane >= off) x += y;
  }
  if (lane == 63) wsum[wid] = x;
  __syncthreads();
  int wpre = 0;
#pragma unroll
  for (int wj = 0; wj < 4; ++wj) wpre += (wj < wid) ? wsum[wj] : 0;
  int excl = wpre + x - sum4;
  int e0 = excl, e1 = excl + h0, e2 = excl + h0 + h1, e3 = excl + h0 + h1 + h2;
  hist[i0] = e0; hist[i0 + 1] = e1; hist[i0 + 2] = e2; hist[i0 + 3] = e3;
  if (i0 + 0 < nn) ptr[n0 + i0 + 0] = beg + e0;
  if (i0 + 1 < nn) ptr[n0 + i0 + 1] = beg + e1;
  if (i0 + 2 < nn) ptr[n0 + i0 + 2] = beg + e2;
  if (i0 + 3 < nn) ptr[n0 + i0 + 3] = beg + e3;
  __syncthreads();
  for (int p = beg + t; p < end; p += 256) {
    int2 r = rec[p];
    int pos = atomicAdd(&hist[r.y - n0], 1);
    out[beg + pos] = r.x;
  }
}

// ---------------- norm_in from row_ptr diffs ---------------------------------
__global__ void norm_in_kernel(const int* __restrict__ row_ptr, float* __restrict__ norm_in) {
  int n = blockIdx.x * blockDim.x + threadIdx.x;
  if (n >= N_NODES) return;
  int deg = row_ptr[n + 1] - row_ptr[n];
  norm_in[n] = sqrtf((float)max(deg, 1));
}

// ---- per-src-node: cs = (1-sg)*ln(S_src) + 0.5*ln(outdeg); wave per node ----
__global__ __launch_bounds__(256) void src_coef(
    const int* __restrict__ col_ptr, const int* __restrict__ row,
    const float4* __restrict__ el4, const float4* __restrict__ er4,
    const float* __restrict__ sigma, float4* __restrict__ cs4) {
  int n = (int)(((size_t)blockIdx.x * blockDim.x + threadIdx.x) >> 6);
  int lane = threadIdx.x & 63;
  if (n >= N_NODES) return;
  int beg = col_ptr[n], end = col_ptr[n + 1];
  float4 o = el4[n];
  float s0 = 0.f, s1 = 0.f, s2 = 0.f, s3 = 0.f;
  for (int p = beg + lane; p < end; p += 64) {
    int u = row[p];
    float4 e = er4[u];
    s0 += __expf(lrelu(e.x + o.x));
    s1 += __expf(lrelu(e.y + o.y));
    s2 += __expf(lrelu(e.z + o.z));
    s3 += __expf(lrelu(e.w + o.w));
  }
#pragma unroll
  for (int off = 32; off; off >>= 1) {
    s0 += __shfl_xor(s0, off); s1 += __shfl_xor(s1, off);
    s2 += __shfl_xor(s2, off); s3 += __shfl_xor(s3, off);
  }
  if (lane == 0) {
    float sg = 1.f / (1.f + __expf(-sigma[0]));
    float c = 0.5f * __logf((float)max(end - beg, 1));
    float k = 1.f - sg;
    cs4[n] = make_float4(k * __logf(s0) + c, k * __logf(s1) + c,
                         k * __logf(s2) + c, k * __logf(s3) + c);
  }
}

// ---- per-dst-node: S_d inline, then w4 = exp(e - sg*lnS_d - cs[src]) --------
__global__ __launch_bounds__(256) void csr_weights(
    const int* __restrict__ row_ptr, const int* __restrict__ col,
    const float4* __restrict__ el4, const float4* __restrict__ er4,
    const float4* __restrict__ cs4, const float* __restrict__ sigma,
    float4* __restrict__ w4) {
  int d = (int)(((size_t)blockIdx.x * blockDim.x + threadIdx.x) >> 6);
  int lane = threadIdx.x & 63;
  if (d >= N_NODES) return;
  int beg = row_ptr[d], end = row_ptr[d + 1];
  if (beg == end) return;
  float4 o = er4[d];
  float s0 = 0.f, s1 = 0.f, s2 = 0.f, s3 = 0.f;
  for (int p = beg + lane; p < end; p += 64) {
    int s_ = col[p];
    float4 e = el4[s_];
    s0 += __expf(lrelu(e.x + o.x));
    s1 += __expf(lrelu(e.y + o.y));
    s2 += __expf(lrelu(e.z + o.z));
    s3 += __expf(lrelu(e.w + o.w));
  }
#pragma unroll
  for (int off = 32; off; off >>= 1) {
    s0 += __shfl_xor(s0, off); s1 += __shfl_xor(s1, off);
    s2 += __shfl_xor(s2, off); s3 += __shfl_xor(s3, off);
  }
  float sg = 1.f / (1.f + __expf(-sigma[0]));
  float c0 = sg * __logf(s0), c1 = sg * __logf(s1);
  float c2 = sg * __logf(s2), c3 = sg * __logf(s3);
  for (int p = beg + lane; p < end; p += 64) {
    int s_ = col[p];
    float4 e = el4[s_];
    float4 cc = cs4[s_];
    float4 wv;
    wv.x = __expf(lrelu(e.x + o.x) - c0 - cc.x);
    wv.y = __expf(lrelu(e.y + o.y) - c1 - cc.y);
    wv.z = __expf(lrelu(e.z + o.z) - c2 - cc.z);
    wv.w = __expf(lrelu(e.w + o.w) - c3 - cc.w);
    w4[p] = wv;
  }
}

// -------- one hop: wave per dst node, unroll-8 edge loop (MLP) ---------------
__global__ __launch_bounds__(256) void hop_kernel(
    const unsigned short* __restrict__ xin, unsigned short* __restrict__ xout,
    const int* __restrict__ row_ptr, const int* __restrict__ col,
    const float* __restrict__ w, const float* __restrict__ norm_in) {
  int d = (int)(((size_t)blockIdx.x * blockDim.x + threadIdx.x) >> 6);
  int lane = threadIdx.x & 63;
  if (d >= N_NODES) return;
  int hh = lane >> 4;
  int beg = row_ptr[d], end = row_ptr[d + 1];
  float a0 = 0.f, a1 = 0.f, a2 = 0.f, a3 = 0.f;
  const unsigned short* xl = xin + lane * 4;
  int p = beg;
  for (; p + 7 < end; p += 8) {
    int sv[8];
    float wv[8];
    ushort4 uv[8];
#pragma unroll
    for (int k = 0; k < 8; ++k) sv[k] = col[p + k];
#pragma unroll
    for (int k = 0; k < 8; ++k) wv[k] = w[(size_t)(p + k) * 4 + hh];
#pragma unroll
    for (int k = 0; k < 8; ++k) uv[k] = *(const ushort4*)(xl + (size_t)sv[k] * HF);
#pragma unroll
    for (int k = 0; k < 8; ++k) {
      a0 = fmaf(wv[k], bf2f(uv[k].x), a0);
      a1 = fmaf(wv[k], bf2f(uv[k].y), a1);
      a2 = fmaf(wv[k], bf2f(uv[k].z), a2);
      a3 = fmaf(wv[k], bf2f(uv[k].w), a3);
    }
  }
  for (; p + 3 < end; p += 4) {
    int s0 = col[p], s1 = col[p + 1], s2 = col[p + 2], s3 = col[p + 3];
    float w0 = w[(size_t)p * 4 + hh];
    float w1 = w[(size_t)p * 4 + 4 + hh];
    float w2 = w[(size_t)p * 4 + 8 + hh];
    float w3 = w[(size_t)p * 4 + 12 + hh];
    ushort4 u0 = *(const ushort4*)(xl + (size_t)s0 * HF);
    ushort4 u1 = *(const ushort4*)(xl + (size_t)s1 * HF);
    ushort4 u2 = *(const ushort4*)(xl + (size_t)s2 * HF);
    ushort4 u3 = *(const ushort4*)(xl + (size_t)s3 * HF);
    a0 = fmaf(w0, bf2f(u0.x), a0); a1 = fmaf(w0, bf2f(u0.y), a1);
    a2 = fmaf(w0, bf2f(u0.z), a2); a3 = fmaf(w0, bf2f(u0.w), a3);
    a0 = fmaf(w1, bf2f(u1.x), a0); a1 = fmaf(w1, bf2f(u1.y), a1);
    a2 = fmaf(w1, bf2f(u1.z), a2); a3 = fmaf(w1, bf2f(u1.w), a3);
    a0 = fmaf(w2, bf2f(u2.x), a0); a1 = fmaf(w2, bf2f(u2.y), a1);
    a2 = fmaf(w2, bf2f(u2.z), a2); a3 = fmaf(w2, bf2f(u2.w), a3);
    a0 = fmaf(w3, bf2f(u3.x), a0); a1 = fmaf(w3, bf2f(u3.y), a1);
    a2 = fmaf(w3, bf2f(u3.z), a2); a3 = fmaf(w3, bf2f(u3.w), a3);
  }
  for (; p < end; ++p) {
    int s = col[p];
    float wt = w[(size_t)p * 4 + hh];
    ushort4 u = *(const ushort4*)(xl + (size_t)s * HF);
    a0 = fmaf(wt, bf2f(u.x), a0); a1 = fmaf(wt, bf2f(u.y), a1);
    a2 = fmaf(wt, bf2f(u.z), a2); a3 = fmaf(wt, bf2f(u.w), a3);
  }
  float ni = norm_in[d];
  ushort4 o;
  o.x = f2bf(a0 * ni); o.y = f2bf(a1 * ni);
  o.z = f2bf(a2 * ni); o.w = f2bf(a3 * ni);
  *(ushort4*)&xout[(size_t)d * HF + lane * 4] = o;
}

// -------- hop-attention softmax over {h, x1, x2, x3} + combine ---------------
__global__ __launch_bounds__(256) void final_combine(
    const unsigned short* __restrict__ h0, const unsigned short* __restrict__ x1,
    const unsigned short* __restrict__ x2, const unsigned short* __restrict__ x3,
    const float* __restrict__ al, const float* __restrict__ hop_attn_r,
    float* __restrict__ out) {
  int n = blockIdx.x, t = threadIdx.x;
  size_t idx = (size_t)n * HF + t;
  float v0 = bf2f(h0[idx]), v1 = bf2f(x1[idx]), v2 = bf2f(x2[idx]), v3 = bf2f(x3[idx]);
  float wr = hop_attn_r[t];
  float b0 = v0 * wr, b1 = v1 * wr, b2 = v2 * wr, b3 = v3 * wr;
#pragma unroll
  for (int off = 32; off; off >>= 1) {
    b0 += __shfl_xor(b0, off);
    b1 += __shfl_xor(b1, off);
    b2 += __shfl_xor(b2, off);
    b3 += __shfl_xor(b3, off);
  }
  float a0 = al[n * 4 + (t >> 6)];
  b0 = lrelu(b0 + a0); b1 = lrelu(b1 + a0); b2 = lrelu(b2 + a0); b3 = lrelu(b3 + a0);
  float m = fmaxf(fmaxf(b0, b1), fmaxf(b2, b3));
  float e0 = expf(b0 - m), e1 = expf(b1 - m), e2 = expf(b2 - m), e3 = expf(b3 - m);
  float inv = 1.f / (e0 + e1 + e2 + e3);
  out[idx] = (v0 * e0 + v1 * e1 + v2 * e2 + v3 * e3) * inv;
}

extern "C" void kernel_launch(void* const* d_in, const int* in_sizes, int n_in,
                              void* d_out, int out_size, void* d_ws, size_t ws_size,
                              hipStream_t stream) {
  const float* feat       = (const float*)d_in[0];
  const int*   src        = (const int*)d_in[1];
  const int*   dst        = (const int*)d_in[2];
  const float* W          = (const float*)d_in[3];
  const float* attn_l     = (const float*)d_in[4];
  const float* attn_r     = (const float*)d_in[5];
  const float* hop_attn_l = (const float*)d_in[6];
  const float* hop_attn_r = (const float*)d_in[7];
  const float* sigma      = (const float*)d_in[8];
  float* out = (float*)d_out;

  char* ws = (char*)d_ws;
  size_t off = 0;
  auto alloc = [&](size_t bytes) -> void* {
    void* p = ws + off;
    off = align256(off + bytes);
    return p;
  };
  unsigned short* h_bf  = (unsigned short*)alloc((size_t)N_NODES * HF * 2); // h, bf16
  unsigned short* x1    = (unsigned short*)alloc((size_t)N_NODES * HF * 2);
  unsigned short* x2    = (unsigned short*)alloc((size_t)N_NODES * HF * 2);
  unsigned short* x3    = (unsigned short*)alloc((size_t)N_NODES * HF * 2);
  float* w_csr  = (float*)alloc((size_t)N_EDGES * 4 * 4);
  int*   col    = (int*)alloc((size_t)N_EDGES * 4);          // CSR payload: src
  int*   row    = (int*)alloc((size_t)N_EDGES * 4);          // CSC payload: dst
  int*   row_ptr= (int*)alloc((size_t)(N_NODES + 1) * 4);
  int*   col_ptr= (int*)alloc((size_t)(N_NODES + 1) * 4);
  float* el     = (float*)alloc((size_t)N_NODES * 4 * 4);
  float* er     = (float*)alloc((size_t)N_NODES * 4 * 4);
  float* al     = (float*)alloc((size_t)N_NODES * 4 * 4);
  float* cs     = (float*)alloc((size_t)N_NODES * 4 * 4);
  float* norm_in= (float*)alloc((size_t)N_NODES * 4);
  unsigned short* W_swz = (unsigned short*)alloc((size_t)65536 * 2);
  int* baseA    = (int*)alloc((size_t)(NBINS + 1) * 4);
  int* baseB    = (int*)alloc((size_t)(NBINS + 1) * 4);
  int* curA     = (int*)alloc((size_t)NBINS * G_SUB * 4);
  int* curB     = (int*)alloc((size_t)NBINS * G_SUB * 4);
  size_t zoff = off;
  int* cntA     = (int*)alloc((size_t)NBINS * G_SUB * 4);
  int* cntB     = (int*)alloc((size_t)NBINS * G_SUB * 4);
  size_t zbytes = off - zoff;
  // edge-record staging aliases bf16 hop buffers (dead before hops run)
  int2* recA = (int2*)x1;
  int2* recB = (int2*)x2;

  hipMemsetAsync(ws + zoff, 0, zbytes, stream);

  // h = feat @ W via bf16 MFMA, fused el/er/al dots, bf16 h out
  w_swizzle<<<256, 256, 0, stream>>>(W, W_swz);
  mfma_gemm<<<(N_NODES + 63) / 64, 256, 0, stream>>>(
      feat, W_swz, h_bf, attn_l, attn_r, hop_attn_l, el, er, al);
  // CSR/CSC build via two-level counting sort (de-contended cursors)
  const int EB = N_EDGES / 256;  // exactly 3125
  bin_hist<<<EB, 256, 0, stream>>>(src, dst, cntA, cntB);
  scan2<<<2, 1024, 0, stream>>>(cntA, curA, baseA, cntB, curB, baseB, row_ptr, col_ptr);
  bin_scatter<<<EB, 256, 0, stream>>>(src, dst, curA, curB, recA, recB);
  bin_sort<<<dim3(NBINS, 2), 256, 0, stream>>>(recA, baseA, row_ptr, col,
                                               recB, baseB, col_ptr, row);
  norm_in_kernel<<<(N_NODES + 255) / 256, 256, 0, stream>>>(row_ptr, norm_in);
  // softmax coefficients + per-edge weights (wave per node, lane per edge)
  const int HB = (N_NODES * 64 + 255) / 256;  // 12500 blocks
  src_coef<<<HB, 256, 0, stream>>>(col_ptr, row, (const float4*)el, (const float4*)er,
                                   sigma, (float4*)cs);
  csr_weights<<<HB, 256, 0, stream>>>(row_ptr, col, (const float4*)el, (const float4*)er,
                                      (const float4*)cs, sigma, (float4*)w_csr);
  // K = 3 hops (bf16 gathers, unroll-8)
  hop_kernel<<<HB, 256, 0, stream>>>(h_bf, x1, row_ptr, col, w_csr, norm_in);
  hop_kernel<<<HB, 256, 0, stream>>>(x1, x2, row_ptr, col, w_csr, norm_in);
  hop_kernel<<<HB, 256, 0, stream>>>(x2, x3, row_ptr, col, w_csr, norm_in);
  // hop-attention combine (all-bf16 hop stack)
  final_combine<<<N_NODES, 256, 0, stream>>>(h_bf, x1, x2, x3, al, hop_attn_r, out);
}